// Round 1
// baseline (60734.235 us; speedup 1.0000x reference)
//
#include <hip/hip_runtime.h>
#include <math.h>

// Problem constants
#define NCOMP 20000
#define SEQT  32
#define INSZ  64
#define HSZ   128
#define EINTRA 640000
#define EINTER 4096
#define NSEC  64

#define LDH 132   // padded LDS row stride (floats): breaks 128-stride bank aliasing, keeps 16B align

__device__ __forceinline__ float dot4f(float4 a, float4 b){
  return a.x*b.x + a.y*b.y + a.z*b.z + a.w*b.w;
}
__device__ __forceinline__ float sigm(float x){ return 1.f/(1.f + __expf(-x)); }
__device__ __forceinline__ float ftanh(float x){
  float cx = fminf(fmaxf(x, -15.f), 15.f);
  float e = __expf(2.f*cx);
  return (e - 1.f)/(e + 1.f);
}
// monotone float<->uint mapping so atomicMax works for signed floats
__device__ __forceinline__ unsigned fordu(float f){
  unsigned b = __float_as_uint(f);
  return (b & 0x80000000u) ? ~b : (b | 0x80000000u);
}
__device__ __forceinline__ float unfordu(unsigned u){
  unsigned b = (u & 0x80000000u) ? (u & 0x7fffffffu) : ~u;
  return __uint_as_float(b);
}
#define NEG_MAX_ORD 0x00800000u   // fordu(-FLT_MAX)

// ---------------------------------------------------------------------------
// Fused 2-layer GRU. Block = 32 companies, 256 threads.
// thread: r = tid>>3 (its company row), dg = tid&7 (16 hidden dims dg*16..+15).
// h0/h1 ping-pong in LDS each step (no intra-step register buffering needed).
// Weights stream from global (all blocks read the same 672KB/step -> L2 hits).
// ---------------------------------------------------------------------------
__global__ __launch_bounds__(256, 2)
void gru2_fused(const float* __restrict__ x,
                const float* __restrict__ wih0, const float* __restrict__ whh0,
                const float* __restrict__ bih0, const float* __restrict__ bhh0,
                const float* __restrict__ wih1, const float* __restrict__ whh1,
                const float* __restrict__ bih1, const float* __restrict__ bhh1,
                float* __restrict__ seq_emb)
{
  __shared__ float sh0[2*32*LDH];
  __shared__ float sh1[2*32*LDH];
  const int tid = threadIdx.x;
  const int r   = tid >> 3;
  const int dg  = tid & 7;
  const int c   = blockIdx.x*32 + r;          // grid is exactly 625*32 = 20000
  const float* xrow = x + (long)c * (SEQT*INSZ);

  for (int i = tid; i < 2*32*LDH; i += 256){ sh0[i] = 0.f; sh1[i] = 0.f; }
  __syncthreads();

  for (int t = 0; t < SEQT; ++t){
    const int rb = t & 1, wbuf = rb ^ 1;
    const float4* xt = (const float4*)(xrow + t*INSZ);
    float* h0r = sh0 + rb  *32*LDH + r*LDH;
    float* h0w = sh0 + wbuf*32*LDH + r*LDH;
    float* h1r = sh1 + rb  *32*LDH + r*LDH;
    float* h1w = sh1 + wbuf*32*LDH + r*LDH;

    // -------- layer 0: input x (K=64), hidden h0 (K=128) --------
    for (int dd = 0; dd < 16; ++dd){
      const int d = dg*16 + dd;
      float ar  = bih0[d]        + bhh0[d];
      float az  = bih0[HSZ+d]    + bhh0[HSZ+d];
      float ain = bih0[2*HSZ+d];
      float ahn = bhh0[2*HSZ+d];
      const float4* wr = (const float4*)(wih0 + d*INSZ);
      const float4* wz = (const float4*)(wih0 + (HSZ+d)*INSZ);
      const float4* wn = (const float4*)(wih0 + (2*HSZ+d)*INSZ);
      #pragma unroll 4
      for (int q = 0; q < INSZ/4; ++q){
        float4 u = xt[q];
        ar  += dot4f(wr[q], u);
        az  += dot4f(wz[q], u);
        ain += dot4f(wn[q], u);
      }
      const float4* hr = (const float4*)(whh0 + d*HSZ);
      const float4* hz = (const float4*)(whh0 + (HSZ+d)*HSZ);
      const float4* hn = (const float4*)(whh0 + (2*HSZ+d)*HSZ);
      const float4* hp = (const float4*)h0r;
      #pragma unroll 4
      for (int q = 0; q < HSZ/4; ++q){
        float4 u = hp[q];
        ar  += dot4f(hr[q], u);
        az  += dot4f(hz[q], u);
        ahn += dot4f(hn[q], u);
      }
      float rg = sigm(ar);
      float zg = sigm(az);
      float ng = ftanh(ain + rg*ahn);
      h0w[d] = (1.f - zg)*ng + zg*h0r[d];
    }
    __syncthreads();

    // -------- layer 1: input = new h0 (K=128), hidden h1 (K=128) --------
    for (int dd = 0; dd < 16; ++dd){
      const int d = dg*16 + dd;
      float ar  = bih1[d]        + bhh1[d];
      float az  = bih1[HSZ+d]    + bhh1[HSZ+d];
      float ain = bih1[2*HSZ+d];
      float ahn = bhh1[2*HSZ+d];
      const float4* wr = (const float4*)(wih1 + d*HSZ);
      const float4* wz = (const float4*)(wih1 + (HSZ+d)*HSZ);
      const float4* wn = (const float4*)(wih1 + (2*HSZ+d)*HSZ);
      const float4* xp = (const float4*)h0w;
      #pragma unroll 4
      for (int q = 0; q < HSZ/4; ++q){
        float4 u = xp[q];
        ar  += dot4f(wr[q], u);
        az  += dot4f(wz[q], u);
        ain += dot4f(wn[q], u);
      }
      const float4* hr = (const float4*)(whh1 + d*HSZ);
      const float4* hz = (const float4*)(whh1 + (HSZ+d)*HSZ);
      const float4* hn = (const float4*)(whh1 + (2*HSZ+d)*HSZ);
      const float4* hp = (const float4*)h1r;
      #pragma unroll 4
      for (int q = 0; q < HSZ/4; ++q){
        float4 u = hp[q];
        ar  += dot4f(hr[q], u);
        az  += dot4f(hz[q], u);
        ahn += dot4f(hn[q], u);
      }
      float rg = sigm(ar);
      float zg = sigm(az);
      float ng = ftanh(ain + rg*ahn);
      h1w[d] = (1.f - zg)*ng + zg*h1r[d];
    }
    __syncthreads();
  }
  // SEQT=32 (even): final h1 lives in buffer 0
  {
    const float* hf = sh1 + r*LDH;
    for (int dd = 0; dd < 16; ++dd){
      int d = dg*16 + dd;
      seq_emb[(long)c*HSZ + d] = hf[d];
    }
  }
}

// ---------------------------------------------------------------------------
// GAT linear transform: H = X @ W^T plus attention logits e_src/e_dst per row.
// Block = 64 rows, 256 threads; thread handles 2 rows x 16 cols.
// ---------------------------------------------------------------------------
__global__ __launch_bounds__(256)
void gat_transform(const float* __restrict__ X, const float* __restrict__ W,
                   const float* __restrict__ asrc, const float* __restrict__ adst,
                   float* __restrict__ Hout, float* __restrict__ es, float* __restrict__ ed,
                   int n)
{
  __shared__ float sX[64*LDH];
  const int tid = threadIdx.x;
  const long base = (long)blockIdx.x * 64;
  for (int i = tid; i < 64*32; i += 256){
    int row = i >> 5, q = i & 31;
    long gr = base + row;
    float4 v = make_float4(0.f, 0.f, 0.f, 0.f);
    if (gr < n) v = ((const float4*)(X + gr*HSZ))[q];
    ((float4*)(sX + row*LDH))[q] = v;
  }
  __syncthreads();
  const int rp = tid >> 3, dg = tid & 7;
  const int r0 = rp*2, r1 = r0 + 1;
  const float4* xa = (const float4*)(sX + r0*LDH);
  const float4* xb = (const float4*)(sX + r1*LDH);
  float ps0=0.f, pd0=0.f, ps1=0.f, pd1=0.f;
  for (int dd = 0; dd < 16; ++dd){
    const int cidx = dg*16 + dd;
    const float4* wp = (const float4*)(W + cidx*HSZ);
    float a0 = 0.f, a1 = 0.f;
    #pragma unroll 4
    for (int q = 0; q < 32; ++q){
      float4 w = wp[q];
      a0 += dot4f(w, xa[q]);
      a1 += dot4f(w, xb[q]);
    }
    float s = asrc[cidx], dv = adst[cidx];
    ps0 += a0*s; pd0 += a0*dv;
    ps1 += a1*s; pd1 += a1*dv;
    if (base + r0 < n) Hout[(base+r0)*HSZ + cidx] = a0;
    if (base + r1 < n) Hout[(base+r1)*HSZ + cidx] = a1;
  }
  #pragma unroll
  for (int m = 1; m < 8; m <<= 1){
    ps0 += __shfl_xor(ps0, m, 64);
    pd0 += __shfl_xor(pd0, m, 64);
    ps1 += __shfl_xor(ps1, m, 64);
    pd1 += __shfl_xor(pd1, m, 64);
  }
  if (dg == 0){
    if (base + r0 < n){ es[base+r0] = ps0; ed[base+r0] = pd0; }
    if (base + r1 < n){ es[base+r1] = ps1; ed[base+r1] = pd1; }
  }
}

// init: per-node max (ord) + denom, per-(node,dim) accumulator, optional sector-ord
__global__ void gat_init(unsigned* __restrict__ maxb, float* __restrict__ den,
                         float* __restrict__ acc, unsigned* __restrict__ sord, int n)
{
  long i = (long)blockIdx.x*256 + threadIdx.x;
  if (i < n){ maxb[i] = NEG_MAX_ORD; den[i] = 0.f; }
  if (i < (long)n*HSZ){
    acc[i] = 0.f;
    if (sord) sord[i] = NEG_MAX_ORD;
  }
}

__global__ void edge_max(const int* __restrict__ src, const int* __restrict__ dst,
                         const float* __restrict__ es, const float* __restrict__ ed,
                         unsigned* __restrict__ maxb, int E, int n)
{
  int i = blockIdx.x*256 + threadIdx.x;
  if (i >= E + n) return;
  int s, d;
  if (i < E){ s = src[i]; d = dst[i]; } else { s = d = i - E; }   // self loops appended
  float e = es[s] + ed[d];
  e = e > 0.f ? e : 0.2f*e;
  atomicMax(maxb + d, fordu(e));
}

__global__ void edge_sum(const int* __restrict__ src, const int* __restrict__ dst,
                         const float* __restrict__ es, const float* __restrict__ ed,
                         const unsigned* __restrict__ maxb, float* __restrict__ den,
                         float* __restrict__ wbuf, int E, int n)
{
  int i = blockIdx.x*256 + threadIdx.x;
  if (i >= E + n) return;
  int s, d;
  if (i < E){ s = src[i]; d = dst[i]; } else { s = d = i - E; }
  float e = es[s] + ed[d];
  e = e > 0.f ? e : 0.2f*e;
  float w = __expf(e - unfordu(maxb[d]));
  wbuf[i] = w;
  atomicAdd(den + d, w);
}

// one thread per (edge, 4-dim chunk): 32 threads cover the 128-dim message
__global__ void edge_scatter(const int* __restrict__ src, const int* __restrict__ dst,
                             const float* __restrict__ wbuf, const float* __restrict__ den,
                             const float* __restrict__ Hv, float* __restrict__ acc,
                             int E, int n)
{
  long t = (long)blockIdx.x*256 + threadIdx.x;
  long i = t >> 5;
  int  j = (int)(t & 31);
  if (i >= E + n) return;
  int s, d;
  if (i < E){ s = src[i]; d = dst[i]; } else { s = d = (int)(i - E); }
  float alpha = wbuf[i] / den[d];
  float4 hv = ((const float4*)(Hv + (long)s*HSZ))[j];
  float* o = acc + (long)d*HSZ + j*4;
  atomicAdd(o+0, alpha*hv.x);
  atomicAdd(o+1, alpha*hv.y);
  atomicAdd(o+2, alpha*hv.z);
  atomicAdd(o+3, alpha*hv.w);
}

// add bias (in place -> intra_emb) and atomicMax into per-sector ord pool
__global__ void bias_pool(float* __restrict__ acc, const float* __restrict__ bias,
                          const int* __restrict__ sid, unsigned* __restrict__ sord, int n)
{
  long i = (long)blockIdx.x*256 + threadIdx.x;
  if (i >= (long)n*HSZ) return;
  int row = (int)(i >> 7), d = (int)(i & 127);
  float v = acc[i] + bias[d];
  acc[i] = v;
  atomicMax(sord + sid[row]*HSZ + d, fordu(v));
}

__global__ void pool_decode(const unsigned* __restrict__ sord, float* __restrict__ spool)
{
  int i = blockIdx.x*256 + threadIdx.x;   // exactly 64*128
  spool[i] = unfordu(sord[i]);
}

__global__ void inter_bias_k(const float* __restrict__ acc2, const float* __restrict__ bias,
                             float* __restrict__ isec)
{
  int i = blockIdx.x*256 + threadIdx.x;   // exactly 64*128
  isec[i] = acc2[i] + bias[i & 127];
}

// out[i] = fusion_b + fw . [seq_emb_i, intra_emb_i, inter_sec[sid_i]]; one wave per company
__global__ __launch_bounds__(256)
void fusion_k(const float* __restrict__ seq, const float* __restrict__ intra,
              const float* __restrict__ isec, const int* __restrict__ sid,
              const float* __restrict__ fw, const float* __restrict__ fb,
              float* __restrict__ out, int n)
{
  int i = blockIdx.x*4 + (threadIdx.x >> 6);
  int l = threadIdx.x & 63;
  if (i >= n) return;
  int sc = sid[i];
  long b = (long)i*HSZ;
  long sb = (long)sc*HSZ;
  float acc = fw[l]     * seq[b + l]      + fw[64 + l]  * seq[b + 64 + l]
            + fw[128+l] * intra[b + l]    + fw[192 + l] * intra[b + 64 + l]
            + fw[256+l] * isec[sb + l]    + fw[320 + l] * isec[sb + 64 + l];
  #pragma unroll
  for (int m = 1; m < 64; m <<= 1) acc += __shfl_xor(acc, m, 64);
  if (l == 0) out[i] = acc + fb[0];
}

// ---------------------------------------------------------------------------
// workspace layout (float offsets); all float4-read bases are 16B aligned
// ---------------------------------------------------------------------------
constexpr long OFF_SEQ    = 0;                      // 20000*128
constexpr long OFF_HINT   = OFF_SEQ   + 2560000;    // 20000*128
constexpr long OFF_ACC    = OFF_HINT  + 2560000;    // 20000*128 (becomes intra_emb)
constexpr long OFF_ES     = OFF_ACC   + 2560000;    // 20000
constexpr long OFF_ED     = OFF_ES    + 20000;
constexpr long OFF_MAX    = OFF_ED    + 20000;      // unsigned
constexpr long OFF_DEN    = OFF_MAX   + 20000;
constexpr long OFF_WBUF   = OFF_DEN   + 20000;      // 660000
constexpr long OFF_SORD   = OFF_WBUF  + 660000;     // 8192 (unsigned)
constexpr long OFF_SPOOL  = OFF_SORD  + 8192;
constexpr long OFF_HINTER = OFF_SPOOL + 8192;
constexpr long OFF_ACC2   = OFF_HINTER+ 8192;
constexpr long OFF_ES2    = OFF_ACC2  + 8192;       // 64
constexpr long OFF_ED2    = OFF_ES2   + 64;
constexpr long OFF_MAX2   = OFF_ED2   + 64;
constexpr long OFF_DEN2   = OFF_MAX2  + 64;
constexpr long OFF_WBUF2  = OFF_DEN2  + 64;         // 4160
constexpr long OFF_ISEC   = OFF_WBUF2 + 4160;       // 8192
// total ~8.47M floats = ~34 MB

extern "C" void kernel_launch(void* const* d_in, const int* in_sizes, int n_in,
                              void* d_out, int out_size, void* d_ws, size_t ws_size,
                              hipStream_t stream)
{
  const float* x    = (const float*)d_in[0];
  const int*   iei  = (const int*)d_in[1];    // [2, 640000]
  const int*   eei  = (const int*)d_in[2];    // [2, 4096]
  const int*   sid  = (const int*)d_in[3];
  const float* wih0 = (const float*)d_in[4];
  const float* whh0 = (const float*)d_in[5];
  const float* bih0 = (const float*)d_in[6];
  const float* bhh0 = (const float*)d_in[7];
  const float* wih1 = (const float*)d_in[8];
  const float* whh1 = (const float*)d_in[9];
  const float* bih1 = (const float*)d_in[10];
  const float* bhh1 = (const float*)d_in[11];
  const float* iW   = (const float*)d_in[12];
  const float* ias  = (const float*)d_in[13];
  const float* iad  = (const float*)d_in[14];
  const float* ib   = (const float*)d_in[15];
  const float* eW   = (const float*)d_in[16];
  const float* eas  = (const float*)d_in[17];
  const float* ead  = (const float*)d_in[18];
  const float* eb   = (const float*)d_in[19];
  const float* fW   = (const float*)d_in[20];
  const float* fb   = (const float*)d_in[21];

  float* ws      = (float*)d_ws;
  float* seq     = ws + OFF_SEQ;
  float* hintra  = ws + OFF_HINT;
  float* acc     = ws + OFF_ACC;
  float* es      = ws + OFF_ES;
  float* ed      = ws + OFF_ED;
  unsigned* mx   = (unsigned*)(ws + OFF_MAX);
  float* den     = ws + OFF_DEN;
  float* wbf     = ws + OFF_WBUF;
  unsigned* sord = (unsigned*)(ws + OFF_SORD);
  float* spool   = ws + OFF_SPOOL;
  float* hinter  = ws + OFF_HINTER;
  float* acc2    = ws + OFF_ACC2;
  float* es2     = ws + OFF_ES2;
  float* ed2     = ws + OFF_ED2;
  unsigned* mx2  = (unsigned*)(ws + OFF_MAX2);
  float* den2    = ws + OFF_DEN2;
  float* wbf2    = ws + OFF_WBUF2;
  float* isec    = ws + OFF_ISEC;

  // 1) fused 2-layer GRU -> seq_emb
  gru2_fused<<<625, 256, 0, stream>>>(x, wih0, whh0, bih0, bhh0,
                                      wih1, whh1, bih1, bhh1, seq);

  // 2) intra GAT
  gat_transform<<<313, 256, 0, stream>>>(seq, iW, ias, iad, hintra, es, ed, NCOMP);
  gat_init<<<10000, 256, 0, stream>>>(mx, den, acc, nullptr, NCOMP);
  gat_init<<<32, 256, 0, stream>>>(mx2, den2, acc2, sord, NSEC);   // also inits sector pool
  {
    int tot = EINTRA + NCOMP;
    edge_max    <<<(tot+255)/256, 256, 0, stream>>>(iei, iei+EINTRA, es, ed, mx, EINTRA, NCOMP);
    edge_sum    <<<(tot+255)/256, 256, 0, stream>>>(iei, iei+EINTRA, es, ed, mx, den, wbf, EINTRA, NCOMP);
    edge_scatter<<<(int)(((long)tot*32)/256), 256, 0, stream>>>(iei, iei+EINTRA, wbf, den, hintra, acc, EINTRA, NCOMP);
  }
  // 3) bias + per-sector max pool
  bias_pool<<<10000, 256, 0, stream>>>(acc, ib, sid, sord, NCOMP);
  pool_decode<<<32, 256, 0, stream>>>(sord, spool);

  // 4) inter GAT (tiny: 64 nodes, 4096 edges)
  gat_transform<<<1, 256, 0, stream>>>(spool, eW, eas, ead, hinter, es2, ed2, NSEC);
  {
    int tot = EINTER + NSEC;
    edge_max    <<<(tot+255)/256, 256, 0, stream>>>(eei, eei+EINTER, es2, ed2, mx2, EINTER, NSEC);
    edge_sum    <<<(tot+255)/256, 256, 0, stream>>>(eei, eei+EINTER, es2, ed2, mx2, den2, wbf2, EINTER, NSEC);
    edge_scatter<<<(tot*32)/256, 256, 0, stream>>>(eei, eei+EINTER, wbf2, den2, hinter, acc2, EINTER, NSEC);
  }
  inter_bias_k<<<32, 256, 0, stream>>>(acc2, eb, isec);

  // 5) fusion -> output [20000]
  fusion_k<<<5000, 256, 0, stream>>>(seq, acc, isec, sid, fW, fb, (float*)d_out, NCOMP);
}

// Round 2
// 12645.800 us; speedup vs baseline: 4.8027x; 4.8027x over previous
//
#include <hip/hip_runtime.h>
#include <math.h>

// Problem constants
#define NCOMP 20000
#define SEQT  32
#define INSZ  64
#define HSZ   128
#define EINTRA 640000
#define EINTER 4096
#define NSEC  64

#define LDH 132   // padded LDS row stride (floats)

__device__ __forceinline__ float dot4f(float4 a, float4 b){
  return a.x*b.x + a.y*b.y + a.z*b.z + a.w*b.w;
}
__device__ __forceinline__ float sigm(float x){ return 1.f/(1.f + __expf(-x)); }
__device__ __forceinline__ float ftanh(float x){
  float cx = fminf(fmaxf(x, -15.f), 15.f);
  float e = __expf(2.f*cx);
  return (e - 1.f)/(e + 1.f);
}
__device__ __forceinline__ float gru_ew(float gir,float giz,float gin,
                                        float hgr,float hgz,float hgn,float hold){
  float r = sigm(gir + hgr);
  float z = sigm(giz + hgz);
  float n = ftanh(gin + r*hgn);
  return (1.f - z)*n + z*hold;
}
// monotone float<->uint mapping so atomicMax works for signed floats
__device__ __forceinline__ unsigned fordu(float f){
  unsigned b = __float_as_uint(f);
  return (b & 0x80000000u) ? ~b : (b | 0x80000000u);
}
__device__ __forceinline__ float unfordu(unsigned u){
  unsigned b = (u & 0x80000000u) ? (u & 0x7fffffffu) : ~u;
  return __uint_as_float(b);
}
#define NEG_MAX_ORD 0x00800000u   // fordu(-FLT_MAX)

// ===========================================================================
// NEW GRU PATH: input-projection GEMMs (weights in registers) + recurrence
// kernels (whh row per thread in registers, h in LDS, broadcast ds_read).
// Time is processed in windows of Tw steps so the gi buffer fits workspace.
// ===========================================================================

// gi = A @ W^T + bias for 80-row tiles. 384 threads; thread g owns W row g
// (K floats in VGPRs). Row r of this window maps to company c=r>>twshift,
// tau=r&(Tw-1); element address = c*cstride + (t0+tau)*K.
template<int K>
__global__ __launch_bounds__(384, 3)
void gi_gemm(const float* __restrict__ A, const float* __restrict__ W,
             const float* __restrict__ bias, float* __restrict__ gi,
             int twshift, int t0, long cstride, int tiles)
{
  constexpr int K4  = K/4;
  constexpr int LDK = K + 4;
  __shared__ float xs[80*LDK];
  const int tid = threadIdx.x;
  const int Twm1 = (1 << twshift) - 1;
  float4 w[K4];
  #pragma unroll
  for (int q = 0; q < K4; ++q) w[q] = ((const float4*)(W + (long)tid*K))[q];
  const float b = bias[tid];

  for (int tile = blockIdx.x; tile < tiles; tile += gridDim.x){
    __syncthreads();                       // xs readers from prev tile done
    for (int idx = tid; idx < 80*K4; idx += 384){
      int row = idx / K4, q = idx & (K4-1);
      int grow = tile*80 + row;
      int c = grow >> twshift, tau = grow & Twm1;
      float4 v = ((const float4*)(A + (long)c*cstride + (long)(t0+tau)*K))[q];
      ((float4*)(xs + row*LDK))[q] = v;
    }
    __syncthreads();
    for (int m0 = 0; m0 < 80; m0 += 4){
      float a0=b, a1=b, a2=b, a3=b;
      const float* xb = xs + m0*LDK;
      #pragma unroll
      for (int q = 0; q < K4; ++q){
        float4 wv = w[q];
        a0 += dot4f(wv, *(const float4*)(xb +           4*q));
        a1 += dot4f(wv, *(const float4*)(xb +   LDK   + 4*q));
        a2 += dot4f(wv, *(const float4*)(xb + 2*LDK   + 4*q));
        a3 += dot4f(wv, *(const float4*)(xb + 3*LDK   + 4*q));
      }
      long ob = ((long)tile*80 + m0)*384 + tid;
      gi[ob]         = a0;
      gi[ob +   384] = a1;
      gi[ob + 2*384] = a2;
      gi[ob + 3*384] = a3;
    }
  }
}

// Recurrence over Tw steps for 40 companies/block. Thread g owns whh row g in
// registers. h[40][132] in LDS; gate pre-activations hg[20][388] staged per
// 20-company half to keep LDS <= 52KB (2 blocks/CU).
__global__ __launch_bounds__(384, 3)
void gru_rec(const float* __restrict__ gi, const float* __restrict__ whh,
             const float* __restrict__ bhh, float* __restrict__ hstate,
             float* __restrict__ outw, int Tw, int t0)
{
  __shared__ float h[40*132];
  __shared__ float hg[20*388];
  const int tid = threadIdx.x;
  const int c0  = blockIdx.x*40;
  float4 w[32];
  #pragma unroll
  for (int q = 0; q < 32; ++q) w[q] = ((const float4*)(whh + (long)tid*128))[q];
  const float bh = bhh[tid];

  if (t0 == 0){
    float4 z4 = make_float4(0.f,0.f,0.f,0.f);
    for (int i = tid; i < 1280; i += 384){
      int m = i>>5, dq = i&31;
      *(float4*)(h + m*132 + dq*4) = z4;
    }
  } else {
    for (int i = tid; i < 1280; i += 384){
      int m = i>>5, dq = i&31;
      *(float4*)(h + m*132 + dq*4) =
          *(const float4*)(hstate + (long)(c0+m)*128 + dq*4);
    }
  }
  __syncthreads();

  for (int tau = 0; tau < Tw; ++tau){
    for (int half = 0; half < 2; ++half){
      const int mb = half*20;
      for (int mg = 0; mg < 20; mg += 4){
        float a0=bh, a1=bh, a2=bh, a3=bh;
        const float* hb = h + (mb+mg)*132;
        #pragma unroll
        for (int q = 0; q < 32; ++q){
          float4 wv = w[q];
          a0 += dot4f(wv, *(const float4*)(hb +           q*4));
          a1 += dot4f(wv, *(const float4*)(hb +   132   + q*4));
          a2 += dot4f(wv, *(const float4*)(hb + 2*132   + q*4));
          a3 += dot4f(wv, *(const float4*)(hb + 3*132   + q*4));
        }
        hg[(mg+0)*388 + tid] = a0;
        hg[(mg+1)*388 + tid] = a1;
        hg[(mg+2)*388 + tid] = a2;
        hg[(mg+3)*388 + tid] = a3;
      }
      __syncthreads();
      // elementwise for these 20 companies (float4 over dims)
      for (int i = tid; i < 640; i += 384){
        int lm = i>>5, dq = i&31;
        int m  = mb + lm;
        long gb = ((long)(c0+m)*Tw + tau)*384;
        float4 gr4 = *(const float4*)(gi + gb +        dq*4);
        float4 gz4 = *(const float4*)(gi + gb + 128 + dq*4);
        float4 gn4 = *(const float4*)(gi + gb + 256 + dq*4);
        const float* hgp = hg + lm*388;
        float4 hr4 = *(const float4*)(hgp +        dq*4);
        float4 hz4 = *(const float4*)(hgp + 128 + dq*4);
        float4 hn4 = *(const float4*)(hgp + 256 + dq*4);
        float* hp = h + m*132 + dq*4;
        float4 ho = *(const float4*)hp;
        float4 hn;
        hn.x = gru_ew(gr4.x, gz4.x, gn4.x, hr4.x, hz4.x, hn4.x, ho.x);
        hn.y = gru_ew(gr4.y, gz4.y, gn4.y, hr4.y, hz4.y, hn4.y, ho.y);
        hn.z = gru_ew(gr4.z, gz4.z, gn4.z, hr4.z, hz4.z, hn4.z, ho.z);
        hn.w = gru_ew(gr4.w, gz4.w, gn4.w, hr4.w, hz4.w, hn4.w, ho.w);
        *(float4*)hp = hn;
        if (outw)
          *(float4*)(outw + ((long)(c0+m)*Tw + tau)*128 + dq*4) = hn;
      }
      __syncthreads();
    }
  }
  for (int i = tid; i < 1280; i += 384){
    int m = i>>5, dq = i&31;
    *(float4*)(hstate + (long)(c0+m)*128 + dq*4) =
        *(const float4*)(h + m*132 + dq*4);
  }
}

// ===========================================================================
// FALLBACK GRU (round-1 kernel, correct but slow) — used only if ws too small
// ===========================================================================
__global__ __launch_bounds__(256, 2)
void gru2_fused(const float* __restrict__ x,
                const float* __restrict__ wih0, const float* __restrict__ whh0,
                const float* __restrict__ bih0, const float* __restrict__ bhh0,
                const float* __restrict__ wih1, const float* __restrict__ whh1,
                const float* __restrict__ bih1, const float* __restrict__ bhh1,
                float* __restrict__ seq_emb)
{
  __shared__ float sh0[2*32*LDH];
  __shared__ float sh1[2*32*LDH];
  const int tid = threadIdx.x;
  const int r   = tid >> 3;
  const int dg  = tid & 7;
  const int c   = blockIdx.x*32 + r;
  const float* xrow = x + (long)c * (SEQT*INSZ);

  for (int i = tid; i < 2*32*LDH; i += 256){ sh0[i] = 0.f; sh1[i] = 0.f; }
  __syncthreads();

  for (int t = 0; t < SEQT; ++t){
    const int rb = t & 1, wbuf = rb ^ 1;
    const float4* xt = (const float4*)(xrow + t*INSZ);
    float* h0r = sh0 + rb  *32*LDH + r*LDH;
    float* h0w = sh0 + wbuf*32*LDH + r*LDH;
    float* h1r = sh1 + rb  *32*LDH + r*LDH;
    float* h1w = sh1 + wbuf*32*LDH + r*LDH;

    for (int dd = 0; dd < 16; ++dd){
      const int d = dg*16 + dd;
      float ar  = bih0[d]        + bhh0[d];
      float az  = bih0[HSZ+d]    + bhh0[HSZ+d];
      float ain = bih0[2*HSZ+d];
      float ahn = bhh0[2*HSZ+d];
      const float4* wr = (const float4*)(wih0 + d*INSZ);
      const float4* wz = (const float4*)(wih0 + (HSZ+d)*INSZ);
      const float4* wn = (const float4*)(wih0 + (2*HSZ+d)*INSZ);
      #pragma unroll 4
      for (int q = 0; q < INSZ/4; ++q){
        float4 u = xt[q];
        ar += dot4f(wr[q], u); az += dot4f(wz[q], u); ain += dot4f(wn[q], u);
      }
      const float4* hr = (const float4*)(whh0 + d*HSZ);
      const float4* hz = (const float4*)(whh0 + (HSZ+d)*HSZ);
      const float4* hn = (const float4*)(whh0 + (2*HSZ+d)*HSZ);
      const float4* hp = (const float4*)h0r;
      #pragma unroll 4
      for (int q = 0; q < HSZ/4; ++q){
        float4 u = hp[q];
        ar += dot4f(hr[q], u); az += dot4f(hz[q], u); ahn += dot4f(hn[q], u);
      }
      float rg = sigm(ar), zg = sigm(az);
      float ng = ftanh(ain + rg*ahn);
      h0w[d] = (1.f - zg)*ng + zg*h0r[d];
    }
    __syncthreads();

    for (int dd = 0; dd < 16; ++dd){
      const int d = dg*16 + dd;
      float ar  = bih1[d]        + bhh1[d];
      float az  = bih1[HSZ+d]    + bhh1[HSZ+d];
      float ain = bih1[2*HSZ+d];
      float ahn = bhh1[2*HSZ+d];
      const float4* wr = (const float4*)(wih1 + d*HSZ);
      const float4* wz = (const float4*)(wih1 + (HSZ+d)*HSZ);
      const float4* wn = (const float4*)(wih1 + (2*HSZ+d)*HSZ);
      const float4* xp = (const float4*)h0w;
      #pragma unroll 4
      for (int q = 0; q < HSZ/4; ++q){
        float4 u = xp[q];
        ar += dot4f(wr[q], u); az += dot4f(wz[q], u); ain += dot4f(wn[q], u);
      }
      const float4* hr = (const float4*)(whh1 + d*HSZ);
      const float4* hz = (const float4*)(whh1 + (HSZ+d)*HSZ);
      const float4* hn = (const float4*)(whh1 + (2*HSZ+d)*HSZ);
      const float4* hp = (const float4*)h1r;
      #pragma unroll 4
      for (int q = 0; q < HSZ/4; ++q){
        float4 u = hp[q];
        ar += dot4f(hr[q], u); az += dot4f(hz[q], u); ahn += dot4f(hn[q], u);
      }
      float rg = sigm(ar), zg = sigm(az);
      float ng = ftanh(ain + rg*ahn);
      h1w[d] = (1.f - zg)*ng + zg*h1r[d];
    }
    __syncthreads();
  }
  {
    const float* hf = sh1 + r*LDH;
    for (int dd = 0; dd < 16; ++dd){
      int d = dg*16 + dd;
      seq_emb[(long)c*HSZ + d] = hf[d];
    }
  }
}

// ===========================================================================
// GAT kernels (unchanged from round 1)
// ===========================================================================
__global__ __launch_bounds__(256)
void gat_transform(const float* __restrict__ X, const float* __restrict__ W,
                   const float* __restrict__ asrc, const float* __restrict__ adst,
                   float* __restrict__ Hout, float* __restrict__ es, float* __restrict__ ed,
                   int n)
{
  __shared__ float sX[64*LDH];
  const int tid = threadIdx.x;
  const long base = (long)blockIdx.x * 64;
  for (int i = tid; i < 64*32; i += 256){
    int row = i >> 5, q = i & 31;
    long gr = base + row;
    float4 v = make_float4(0.f, 0.f, 0.f, 0.f);
    if (gr < n) v = ((const float4*)(X + gr*HSZ))[q];
    ((float4*)(sX + row*LDH))[q] = v;
  }
  __syncthreads();
  const int rp = tid >> 3, dg = tid & 7;
  const int r0 = rp*2, r1 = r0 + 1;
  const float4* xa = (const float4*)(sX + r0*LDH);
  const float4* xb = (const float4*)(sX + r1*LDH);
  float ps0=0.f, pd0=0.f, ps1=0.f, pd1=0.f;
  for (int dd = 0; dd < 16; ++dd){
    const int cidx = dg*16 + dd;
    const float4* wp = (const float4*)(W + cidx*HSZ);
    float a0 = 0.f, a1 = 0.f;
    #pragma unroll 4
    for (int q = 0; q < 32; ++q){
      float4 w = wp[q];
      a0 += dot4f(w, xa[q]);
      a1 += dot4f(w, xb[q]);
    }
    float s = asrc[cidx], dv = adst[cidx];
    ps0 += a0*s; pd0 += a0*dv;
    ps1 += a1*s; pd1 += a1*dv;
    if (base + r0 < n) Hout[(base+r0)*HSZ + cidx] = a0;
    if (base + r1 < n) Hout[(base+r1)*HSZ + cidx] = a1;
  }
  #pragma unroll
  for (int m = 1; m < 8; m <<= 1){
    ps0 += __shfl_xor(ps0, m, 64);
    pd0 += __shfl_xor(pd0, m, 64);
    ps1 += __shfl_xor(ps1, m, 64);
    pd1 += __shfl_xor(pd1, m, 64);
  }
  if (dg == 0){
    if (base + r0 < n){ es[base+r0] = ps0; ed[base+r0] = pd0; }
    if (base + r1 < n){ es[base+r1] = ps1; ed[base+r1] = pd1; }
  }
}

__global__ void gat_init(unsigned* __restrict__ maxb, float* __restrict__ den,
                         float* __restrict__ acc, unsigned* __restrict__ sord, int n)
{
  long i = (long)blockIdx.x*256 + threadIdx.x;
  if (i < n){ maxb[i] = NEG_MAX_ORD; den[i] = 0.f; }
  if (i < (long)n*HSZ){
    acc[i] = 0.f;
    if (sord) sord[i] = NEG_MAX_ORD;
  }
}

__global__ void edge_max(const int* __restrict__ src, const int* __restrict__ dst,
                         const float* __restrict__ es, const float* __restrict__ ed,
                         unsigned* __restrict__ maxb, int E, int n)
{
  int i = blockIdx.x*256 + threadIdx.x;
  if (i >= E + n) return;
  int s, d;
  if (i < E){ s = src[i]; d = dst[i]; } else { s = d = i - E; }
  float e = es[s] + ed[d];
  e = e > 0.f ? e : 0.2f*e;
  atomicMax(maxb + d, fordu(e));
}

__global__ void edge_sum(const int* __restrict__ src, const int* __restrict__ dst,
                         const float* __restrict__ es, const float* __restrict__ ed,
                         const unsigned* __restrict__ maxb, float* __restrict__ den,
                         float* __restrict__ wbuf, int E, int n)
{
  int i = blockIdx.x*256 + threadIdx.x;
  if (i >= E + n) return;
  int s, d;
  if (i < E){ s = src[i]; d = dst[i]; } else { s = d = i - E; }
  float e = es[s] + ed[d];
  e = e > 0.f ? e : 0.2f*e;
  float w = __expf(e - unfordu(maxb[d]));
  wbuf[i] = w;
  atomicAdd(den + d, w);
}

__global__ void edge_scatter(const int* __restrict__ src, const int* __restrict__ dst,
                             const float* __restrict__ wbuf, const float* __restrict__ den,
                             const float* __restrict__ Hv, float* __restrict__ acc,
                             int E, int n)
{
  long t = (long)blockIdx.x*256 + threadIdx.x;
  long i = t >> 5;
  int  j = (int)(t & 31);
  if (i >= E + n) return;
  int s, d;
  if (i < E){ s = src[i]; d = dst[i]; } else { s = d = (int)(i - E); }
  float alpha = wbuf[i] / den[d];
  float4 hv = ((const float4*)(Hv + (long)s*HSZ))[j];
  float* o = acc + (long)d*HSZ + j*4;
  atomicAdd(o+0, alpha*hv.x);
  atomicAdd(o+1, alpha*hv.y);
  atomicAdd(o+2, alpha*hv.z);
  atomicAdd(o+3, alpha*hv.w);
}

__global__ void bias_pool(float* __restrict__ acc, const float* __restrict__ bias,
                          const int* __restrict__ sid, unsigned* __restrict__ sord, int n)
{
  long i = (long)blockIdx.x*256 + threadIdx.x;
  if (i >= (long)n*HSZ) return;
  int row = (int)(i >> 7), d = (int)(i & 127);
  float v = acc[i] + bias[d];
  acc[i] = v;
  atomicMax(sord + sid[row]*HSZ + d, fordu(v));
}

__global__ void pool_decode(const unsigned* __restrict__ sord, float* __restrict__ spool)
{
  int i = blockIdx.x*256 + threadIdx.x;
  spool[i] = unfordu(sord[i]);
}

__global__ void inter_bias_k(const float* __restrict__ acc2, const float* __restrict__ bias,
                             float* __restrict__ isec)
{
  int i = blockIdx.x*256 + threadIdx.x;
  isec[i] = acc2[i] + bias[i & 127];
}

__global__ __launch_bounds__(256)
void fusion_k(const float* __restrict__ seq, const float* __restrict__ intra,
              const float* __restrict__ isec, const int* __restrict__ sid,
              const float* __restrict__ fw, const float* __restrict__ fb,
              float* __restrict__ out, int n)
{
  int i = blockIdx.x*4 + (threadIdx.x >> 6);
  int l = threadIdx.x & 63;
  if (i >= n) return;
  int sc = sid[i];
  long b = (long)i*HSZ;
  long sb = (long)sc*HSZ;
  float acc = fw[l]     * seq[b + l]      + fw[64 + l]  * seq[b + 64 + l]
            + fw[128+l] * intra[b + l]    + fw[192 + l] * intra[b + 64 + l]
            + fw[256+l] * isec[sb + l]    + fw[320 + l] * isec[sb + 64 + l];
  #pragma unroll
  for (int m = 1; m < 64; m <<= 1) acc += __shfl_xor(acc, m, 64);
  if (l == 0) out[i] = acc + fb[0];
}

extern "C" void kernel_launch(void* const* d_in, const int* in_sizes, int n_in,
                              void* d_out, int out_size, void* d_ws, size_t ws_size,
                              hipStream_t stream)
{
  const float* x    = (const float*)d_in[0];
  const int*   iei  = (const int*)d_in[1];
  const int*   eei  = (const int*)d_in[2];
  const int*   sid  = (const int*)d_in[3];
  const float* wih0 = (const float*)d_in[4];
  const float* whh0 = (const float*)d_in[5];
  const float* bih0 = (const float*)d_in[6];
  const float* bhh0 = (const float*)d_in[7];
  const float* wih1 = (const float*)d_in[8];
  const float* whh1 = (const float*)d_in[9];
  const float* bih1 = (const float*)d_in[10];
  const float* bhh1 = (const float*)d_in[11];
  const float* iW   = (const float*)d_in[12];
  const float* ias  = (const float*)d_in[13];
  const float* iad  = (const float*)d_in[14];
  const float* ib   = (const float*)d_in[15];
  const float* eW   = (const float*)d_in[16];
  const float* eas  = (const float*)d_in[17];
  const float* ead  = (const float*)d_in[18];
  const float* eb   = (const float*)d_in[19];
  const float* fW   = (const float*)d_in[20];
  const float* fb   = (const float*)d_in[21];

  float* ws = (float*)d_ws;
  const long avail = (long)(ws_size / 4);

  // pick time-window Tw so gi/out0 window buffers fit workspace
  int Tw = 0;
  for (int cand = 8; cand >= 1; cand >>= 1){
    if (10240000L*cand + 11025376L <= avail){ Tw = cand; break; }
  }

  const float* seq = nullptr;   // seq_emb pointer for the GAT stage
  float *hintra, *acc, *es, *ed, *den, *wbf, *spool, *hinter, *acc2;
  float *es2, *ed2, *den2, *wbf2, *isec;
  unsigned *mx, *sord, *mx2;

  if (Tw > 0){
    // ---- new-path workspace layout ----
    long off = 0;
    float* h0s   = ws + off; off += 2560000;
    float* h1s   = ws + off; off += 2560000;        // final = seq_emb
    float* giW   = ws + off; off += 20000L*Tw*384;
    float* out0W = ws + off; off += 20000L*Tw*128;
    hintra = ws + off; off += 2560000;
    acc    = ws + off; off += 2560000;
    es  = ws + off; off += 20000;
    ed  = ws + off; off += 20000;
    mx  = (unsigned*)(ws + off); off += 20000;
    den = ws + off; off += 20000;
    wbf = ws + off; off += 660000;
    sord  = (unsigned*)(ws + off); off += 8192;
    spool = ws + off; off += 8192;
    hinter= ws + off; off += 8192;
    acc2  = ws + off; off += 8192;
    es2 = ws + off; off += 64;
    ed2 = ws + off; off += 64;
    mx2 = (unsigned*)(ws + off); off += 64;
    den2= ws + off; off += 64;
    wbf2= ws + off; off += 4160;
    isec= ws + off; off += 8192;

    const int twshift = __builtin_ctz(Tw);
    const int tiles   = 250*Tw;          // (20000*Tw)/80
    const int NW      = 32/Tw;
    for (int w = 0; w < NW; ++w){
      const int t0 = w*Tw;
      gi_gemm<64> <<<tiles, 384, 0, stream>>>(x,     wih0, bih0, giW, twshift, t0, 2048L,          tiles);
      gru_rec     <<<500,   384, 0, stream>>>(giW, whh0, bhh0, h0s, out0W, Tw, t0);
      gi_gemm<128><<<tiles, 384, 0, stream>>>(out0W, wih1, bih1, giW, twshift, 0, (long)Tw*128, tiles);
      gru_rec     <<<500,   384, 0, stream>>>(giW, whh1, bhh1, h1s, nullptr, Tw, t0);
    }
    seq = h1s;
  } else {
    // ---- fallback: round-1 layout + slow fused GRU ----
    long off = 0;
    float* seqb = ws + off; off += 2560000;
    hintra = ws + off; off += 2560000;
    acc    = ws + off; off += 2560000;
    es  = ws + off; off += 20000;
    ed  = ws + off; off += 20000;
    mx  = (unsigned*)(ws + off); off += 20000;
    den = ws + off; off += 20000;
    wbf = ws + off; off += 660000;
    sord  = (unsigned*)(ws + off); off += 8192;
    spool = ws + off; off += 8192;
    hinter= ws + off; off += 8192;
    acc2  = ws + off; off += 8192;
    es2 = ws + off; off += 64;
    ed2 = ws + off; off += 64;
    mx2 = (unsigned*)(ws + off); off += 64;
    den2= ws + off; off += 64;
    wbf2= ws + off; off += 4160;
    isec= ws + off; off += 8192;

    gru2_fused<<<625, 256, 0, stream>>>(x, wih0, whh0, bih0, bhh0,
                                        wih1, whh1, bih1, bhh1, seqb);
    seq = seqb;
  }

  // ---- GAT stage (unchanged) ----
  gat_transform<<<313, 256, 0, stream>>>(seq, iW, ias, iad, hintra, es, ed, NCOMP);
  gat_init<<<10000, 256, 0, stream>>>(mx, den, acc, nullptr, NCOMP);
  gat_init<<<32, 256, 0, stream>>>(mx2, den2, acc2, sord, NSEC);
  {
    int tot = EINTRA + NCOMP;
    edge_max    <<<(tot+255)/256, 256, 0, stream>>>(iei, iei+EINTRA, es, ed, mx, EINTRA, NCOMP);
    edge_sum    <<<(tot+255)/256, 256, 0, stream>>>(iei, iei+EINTRA, es, ed, mx, den, wbf, EINTRA, NCOMP);
    edge_scatter<<<(int)(((long)tot*32)/256), 256, 0, stream>>>(iei, iei+EINTRA, wbf, den, hintra, acc, EINTRA, NCOMP);
  }
  bias_pool<<<10000, 256, 0, stream>>>(acc, ib, sid, sord, NCOMP);
  pool_decode<<<32, 256, 0, stream>>>(sord, spool);

  gat_transform<<<1, 256, 0, stream>>>(spool, eW, eas, ead, hinter, es2, ed2, NSEC);
  {
    int tot = EINTER + NSEC;
    edge_max    <<<(tot+255)/256, 256, 0, stream>>>(eei, eei+EINTER, es2, ed2, mx2, EINTER, NSEC);
    edge_sum    <<<(tot+255)/256, 256, 0, stream>>>(eei, eei+EINTER, es2, ed2, mx2, den2, wbf2, EINTER, NSEC);
    edge_scatter<<<(tot*32)/256, 256, 0, stream>>>(eei, eei+EINTER, wbf2, den2, hinter, acc2, EINTER, NSEC);
  }
  inter_bias_k<<<32, 256, 0, stream>>>(acc2, eb, isec);

  fusion_k<<<5000, 256, 0, stream>>>(seq, acc, isec, sid, fW, fb, (float*)d_out, NCOMP);
}

// Round 3
// 12603.278 us; speedup vs baseline: 4.8189x; 1.0034x over previous
//
#include <hip/hip_runtime.h>
#include <math.h>

// Problem constants
#define NCOMP 20000
#define SEQT  32
#define INSZ  64
#define HSZ   128
#define EINTRA 640000
#define EINTER 4096
#define NSEC  64

#define LDH 132   // padded LDS row stride (floats)

__device__ __forceinline__ float dot4f(float4 a, float4 b){
  return a.x*b.x + a.y*b.y + a.z*b.z + a.w*b.w;
}
__device__ __forceinline__ float sigm(float x){ return 1.f/(1.f + __expf(-x)); }
__device__ __forceinline__ float ftanh(float x){
  float cx = fminf(fmaxf(x, -15.f), 15.f);
  float e = __expf(2.f*cx);
  return (e - 1.f)/(e + 1.f);
}
__device__ __forceinline__ float gru_ew(float gir,float giz,float gin,
                                        float hgr,float hgz,float hgn,float hold){
  float r = sigm(gir + hgr);
  float z = sigm(giz + hgz);
  float n = ftanh(gin + r*hgn);
  return (1.f - z)*n + z*hold;
}
// monotone float<->uint mapping so atomicMax works for signed floats
__device__ __forceinline__ unsigned fordu(float f){
  unsigned b = __float_as_uint(f);
  return (b & 0x80000000u) ? ~b : (b | 0x80000000u);
}
__device__ __forceinline__ float unfordu(unsigned u){
  unsigned b = (u & 0x80000000u) ? (u & 0x7fffffffu) : ~u;
  return __uint_as_float(b);
}
#define NEG_MAX_ORD 0x00800000u   // fordu(-FLT_MAX)

// ===========================================================================
// GRU PATH: input-projection GEMMs (weights in registers) + recurrence
// kernels (whh row per thread in registers, h in LDS, broadcast ds_read).
// launch_bounds min-waves chosen so the per-thread weight row NEVER spills:
//   K=64  -> 64 VGPRs of weights -> cap 170 ok  (384,3)
//   K=128 -> 128 VGPRs of weights -> needs cap 256 (384,2)   [R2 bug: (384,3)
//            capped at ~170 and the compiler spilled w[] to scratch]
// ===========================================================================

// gi = A @ W^T + bias for 80-row tiles. Thread g owns W row g (K floats in
// VGPRs). Row r of window: company c=r>>twshift, tau=r&(Tw-1).
__global__ __launch_bounds__(384, 3)
void gi_gemm64(const float* __restrict__ A, const float* __restrict__ W,
               const float* __restrict__ bias, float* __restrict__ gi,
               int twshift, int t0, long cstride, int tiles)
{
  constexpr int K = 64, K4 = K/4, LDK = K + 4;
  __shared__ float xs[80*LDK];
  const int tid = threadIdx.x;
  const int Twm1 = (1 << twshift) - 1;
  float4 w[K4];
  #pragma unroll
  for (int q = 0; q < K4; ++q) w[q] = ((const float4*)(W + (long)tid*K))[q];
  const float b = bias[tid];

  for (int tile = blockIdx.x; tile < tiles; tile += gridDim.x){
    __syncthreads();
    for (int idx = tid; idx < 80*K4; idx += 384){
      int row = idx / K4, q = idx & (K4-1);
      int grow = tile*80 + row;
      int c = grow >> twshift, tau = grow & Twm1;
      float4 v = ((const float4*)(A + (long)c*cstride + (long)(t0+tau)*K))[q];
      ((float4*)(xs + row*LDK))[q] = v;
    }
    __syncthreads();
    for (int m0 = 0; m0 < 80; m0 += 4){
      float a0=b, a1=b, a2=b, a3=b;
      const float* xb = xs + m0*LDK;
      #pragma unroll
      for (int q = 0; q < K4; ++q){
        float4 wv = w[q];
        a0 += dot4f(wv, *(const float4*)(xb +         4*q));
        a1 += dot4f(wv, *(const float4*)(xb +   LDK + 4*q));
        a2 += dot4f(wv, *(const float4*)(xb + 2*LDK + 4*q));
        a3 += dot4f(wv, *(const float4*)(xb + 3*LDK + 4*q));
      }
      long ob = ((long)tile*80 + m0)*384 + tid;
      gi[ob]         = a0;
      gi[ob +   384] = a1;
      gi[ob + 2*384] = a2;
      gi[ob + 3*384] = a3;
    }
  }
}

__global__ __launch_bounds__(384, 2)
void gi_gemm128(const float* __restrict__ A, const float* __restrict__ W,
                const float* __restrict__ bias, float* __restrict__ gi,
                int twshift, int t0, long cstride, int tiles)
{
  constexpr int K = 128, K4 = K/4, LDK = K + 4;
  __shared__ float xs[80*LDK];
  const int tid = threadIdx.x;
  const int Twm1 = (1 << twshift) - 1;
  float4 w[K4];
  #pragma unroll
  for (int q = 0; q < K4; ++q) w[q] = ((const float4*)(W + (long)tid*K))[q];
  const float b = bias[tid];

  for (int tile = blockIdx.x; tile < tiles; tile += gridDim.x){
    __syncthreads();
    for (int idx = tid; idx < 80*K4; idx += 384){
      int row = idx / K4, q = idx & (K4-1);
      int grow = tile*80 + row;
      int c = grow >> twshift, tau = grow & Twm1;
      float4 v = ((const float4*)(A + (long)c*cstride + (long)(t0+tau)*K))[q];
      ((float4*)(xs + row*LDK))[q] = v;
    }
    __syncthreads();
    for (int m0 = 0; m0 < 80; m0 += 4){
      float a0=b, a1=b, a2=b, a3=b;
      const float* xb = xs + m0*LDK;
      #pragma unroll
      for (int q = 0; q < K4; ++q){
        float4 wv = w[q];
        a0 += dot4f(wv, *(const float4*)(xb +         4*q));
        a1 += dot4f(wv, *(const float4*)(xb +   LDK + 4*q));
        a2 += dot4f(wv, *(const float4*)(xb + 2*LDK + 4*q));
        a3 += dot4f(wv, *(const float4*)(xb + 3*LDK + 4*q));
      }
      long ob = ((long)tile*80 + m0)*384 + tid;
      gi[ob]         = a0;
      gi[ob +   384] = a1;
      gi[ob + 2*384] = a2;
      gi[ob + 3*384] = a3;
    }
  }
}

// Recurrence over Tw steps for 40 companies/block. Thread g owns whh row g
// (32 float4 = 128 VGPRs — (384,2) so it does NOT spill). h[40][132] and full
// gate staging hg[40][388] in LDS (83 KB -> 1 block/CU; fine, we're
// VGPR-limited to 1 block anyway). 2 barriers per timestep.
__global__ __launch_bounds__(384, 2)
void gru_rec(const float* __restrict__ gi, const float* __restrict__ whh,
             const float* __restrict__ bhh, float* __restrict__ hstate,
             float* __restrict__ outw, int Tw, int t0)
{
  __shared__ float h[40*132];
  __shared__ float hg[40*388];
  const int tid = threadIdx.x;
  const int c0  = blockIdx.x*40;
  float4 w[32];
  #pragma unroll
  for (int q = 0; q < 32; ++q) w[q] = ((const float4*)(whh + (long)tid*128))[q];
  const float bh = bhh[tid];

  if (t0 == 0){
    float4 z4 = make_float4(0.f,0.f,0.f,0.f);
    for (int i = tid; i < 1280; i += 384){
      int m = i>>5, dq = i&31;
      *(float4*)(h + m*132 + dq*4) = z4;
    }
  } else {
    for (int i = tid; i < 1280; i += 384){
      int m = i>>5, dq = i&31;
      *(float4*)(h + m*132 + dq*4) =
          *(const float4*)(hstate + (long)(c0+m)*128 + dq*4);
    }
  }
  __syncthreads();

  for (int tau = 0; tau < Tw; ++tau){
    // GEMV: hg[m][g] = bhh[g] + whh[g,:] . h[m,:]   (broadcast LDS reads)
    for (int mg = 0; mg < 40; mg += 4){
      float a0=bh, a1=bh, a2=bh, a3=bh;
      const float* hb = h + mg*132;
      #pragma unroll
      for (int q = 0; q < 32; ++q){
        float4 wv = w[q];
        a0 += dot4f(wv, *(const float4*)(hb +         q*4));
        a1 += dot4f(wv, *(const float4*)(hb +   132 + q*4));
        a2 += dot4f(wv, *(const float4*)(hb + 2*132 + q*4));
        a3 += dot4f(wv, *(const float4*)(hb + 3*132 + q*4));
      }
      hg[(mg+0)*388 + tid] = a0;
      hg[(mg+1)*388 + tid] = a1;
      hg[(mg+2)*388 + tid] = a2;
      hg[(mg+3)*388 + tid] = a3;
    }
    __syncthreads();
    // elementwise over all 40 companies x 32 float4-dims
    for (int i = tid; i < 1280; i += 384){
      int m = i>>5, dq = i&31;
      long gb = ((long)(c0+m)*Tw + tau)*384;
      float4 gr4 = *(const float4*)(gi + gb +       dq*4);
      float4 gz4 = *(const float4*)(gi + gb + 128 + dq*4);
      float4 gn4 = *(const float4*)(gi + gb + 256 + dq*4);
      const float* hgp = hg + m*388;
      float4 hr4 = *(const float4*)(hgp +       dq*4);
      float4 hz4 = *(const float4*)(hgp + 128 + dq*4);
      float4 hn4 = *(const float4*)(hgp + 256 + dq*4);
      float* hp = h + m*132 + dq*4;
      float4 ho = *(const float4*)hp;
      float4 hn;
      hn.x = gru_ew(gr4.x, gz4.x, gn4.x, hr4.x, hz4.x, hn4.x, ho.x);
      hn.y = gru_ew(gr4.y, gz4.y, gn4.y, hr4.y, hz4.y, hn4.y, ho.y);
      hn.z = gru_ew(gr4.z, gz4.z, gn4.z, hr4.z, hz4.z, hn4.z, ho.z);
      hn.w = gru_ew(gr4.w, gz4.w, gn4.w, hr4.w, hz4.w, hn4.w, ho.w);
      *(float4*)hp = hn;
      if (outw)
        *(float4*)(outw + ((long)(c0+m)*Tw + tau)*128 + dq*4) = hn;
    }
    __syncthreads();
  }
  for (int i = tid; i < 1280; i += 384){
    int m = i>>5, dq = i&31;
    *(float4*)(hstate + (long)(c0+m)*128 + dq*4) =
        *(const float4*)(h + m*132 + dq*4);
  }
}

// ===========================================================================
// FALLBACK GRU (round-1 kernel, correct but slow) — used only if ws too small
// ===========================================================================
__global__ __launch_bounds__(256, 2)
void gru2_fused(const float* __restrict__ x,
                const float* __restrict__ wih0, const float* __restrict__ whh0,
                const float* __restrict__ bih0, const float* __restrict__ bhh0,
                const float* __restrict__ wih1, const float* __restrict__ whh1,
                const float* __restrict__ bih1, const float* __restrict__ bhh1,
                float* __restrict__ seq_emb)
{
  __shared__ float sh0[2*32*LDH];
  __shared__ float sh1[2*32*LDH];
  const int tid = threadIdx.x;
  const int r   = tid >> 3;
  const int dg  = tid & 7;
  const int c   = blockIdx.x*32 + r;
  const float* xrow = x + (long)c * (SEQT*INSZ);

  for (int i = tid; i < 2*32*LDH; i += 256){ sh0[i] = 0.f; sh1[i] = 0.f; }
  __syncthreads();

  for (int t = 0; t < SEQT; ++t){
    const int rb = t & 1, wbuf = rb ^ 1;
    const float4* xt = (const float4*)(xrow + t*INSZ);
    float* h0r = sh0 + rb  *32*LDH + r*LDH;
    float* h0w = sh0 + wbuf*32*LDH + r*LDH;
    float* h1r = sh1 + rb  *32*LDH + r*LDH;
    float* h1w = sh1 + wbuf*32*LDH + r*LDH;

    for (int dd = 0; dd < 16; ++dd){
      const int d = dg*16 + dd;
      float ar  = bih0[d]        + bhh0[d];
      float az  = bih0[HSZ+d]    + bhh0[HSZ+d];
      float ain = bih0[2*HSZ+d];
      float ahn = bhh0[2*HSZ+d];
      const float4* wr = (const float4*)(wih0 + d*INSZ);
      const float4* wz = (const float4*)(wih0 + (HSZ+d)*INSZ);
      const float4* wn = (const float4*)(wih0 + (2*HSZ+d)*INSZ);
      #pragma unroll 4
      for (int q = 0; q < INSZ/4; ++q){
        float4 u = xt[q];
        ar += dot4f(wr[q], u); az += dot4f(wz[q], u); ain += dot4f(wn[q], u);
      }
      const float4* hr = (const float4*)(whh0 + d*HSZ);
      const float4* hz = (const float4*)(whh0 + (HSZ+d)*HSZ);
      const float4* hn = (const float4*)(whh0 + (2*HSZ+d)*HSZ);
      const float4* hp = (const float4*)h0r;
      #pragma unroll 4
      for (int q = 0; q < HSZ/4; ++q){
        float4 u = hp[q];
        ar += dot4f(hr[q], u); az += dot4f(hz[q], u); ahn += dot4f(hn[q], u);
      }
      float rg = sigm(ar), zg = sigm(az);
      float ng = ftanh(ain + rg*ahn);
      h0w[d] = (1.f - zg)*ng + zg*h0r[d];
    }
    __syncthreads();

    for (int dd = 0; dd < 16; ++dd){
      const int d = dg*16 + dd;
      float ar  = bih1[d]        + bhh1[d];
      float az  = bih1[HSZ+d]    + bhh1[HSZ+d];
      float ain = bih1[2*HSZ+d];
      float ahn = bhh1[2*HSZ+d];
      const float4* wr = (const float4*)(wih1 + d*HSZ);
      const float4* wz = (const float4*)(wih1 + (HSZ+d)*HSZ);
      const float4* wn = (const float4*)(wih1 + (2*HSZ+d)*HSZ);
      const float4* xp = (const float4*)h0w;
      #pragma unroll 4
      for (int q = 0; q < HSZ/4; ++q){
        float4 u = xp[q];
        ar += dot4f(wr[q], u); az += dot4f(wz[q], u); ain += dot4f(wn[q], u);
      }
      const float4* hr = (const float4*)(whh1 + d*HSZ);
      const float4* hz = (const float4*)(whh1 + (HSZ+d)*HSZ);
      const float4* hn = (const float4*)(whh1 + (2*HSZ+d)*HSZ);
      const float4* hp = (const float4*)h1r;
      #pragma unroll 4
      for (int q = 0; q < HSZ/4; ++q){
        float4 u = hp[q];
        ar += dot4f(hr[q], u); az += dot4f(hz[q], u); ahn += dot4f(hn[q], u);
      }
      float rg = sigm(ar), zg = sigm(az);
      float ng = ftanh(ain + rg*ahn);
      h1w[d] = (1.f - zg)*ng + zg*h1r[d];
    }
    __syncthreads();
  }
  {
    const float* hf = sh1 + r*LDH;
    for (int dd = 0; dd < 16; ++dd){
      int d = dg*16 + dd;
      seq_emb[(long)c*HSZ + d] = hf[d];
    }
  }
}

// ===========================================================================
// GAT kernels (unchanged)
// ===========================================================================
__global__ __launch_bounds__(256)
void gat_transform(const float* __restrict__ X, const float* __restrict__ W,
                   const float* __restrict__ asrc, const float* __restrict__ adst,
                   float* __restrict__ Hout, float* __restrict__ es, float* __restrict__ ed,
                   int n)
{
  __shared__ float sX[64*LDH];
  const int tid = threadIdx.x;
  const long base = (long)blockIdx.x * 64;
  for (int i = tid; i < 64*32; i += 256){
    int row = i >> 5, q = i & 31;
    long gr = base + row;
    float4 v = make_float4(0.f, 0.f, 0.f, 0.f);
    if (gr < n) v = ((const float4*)(X + gr*HSZ))[q];
    ((float4*)(sX + row*LDH))[q] = v;
  }
  __syncthreads();
  const int rp = tid >> 3, dg = tid & 7;
  const int r0 = rp*2, r1 = r0 + 1;
  const float4* xa = (const float4*)(sX + r0*LDH);
  const float4* xb = (const float4*)(sX + r1*LDH);
  float ps0=0.f, pd0=0.f, ps1=0.f, pd1=0.f;
  for (int dd = 0; dd < 16; ++dd){
    const int cidx = dg*16 + dd;
    const float4* wp = (const float4*)(W + cidx*HSZ);
    float a0 = 0.f, a1 = 0.f;
    #pragma unroll 4
    for (int q = 0; q < 32; ++q){
      float4 w = wp[q];
      a0 += dot4f(w, xa[q]);
      a1 += dot4f(w, xb[q]);
    }
    float s = asrc[cidx], dv = adst[cidx];
    ps0 += a0*s; pd0 += a0*dv;
    ps1 += a1*s; pd1 += a1*dv;
    if (base + r0 < n) Hout[(base+r0)*HSZ + cidx] = a0;
    if (base + r1 < n) Hout[(base+r1)*HSZ + cidx] = a1;
  }
  #pragma unroll
  for (int m = 1; m < 8; m <<= 1){
    ps0 += __shfl_xor(ps0, m, 64);
    pd0 += __shfl_xor(pd0, m, 64);
    ps1 += __shfl_xor(ps1, m, 64);
    pd1 += __shfl_xor(pd1, m, 64);
  }
  if (dg == 0){
    if (base + r0 < n){ es[base+r0] = ps0; ed[base+r0] = pd0; }
    if (base + r1 < n){ es[base+r1] = ps1; ed[base+r1] = pd1; }
  }
}

__global__ void gat_init(unsigned* __restrict__ maxb, float* __restrict__ den,
                         float* __restrict__ acc, unsigned* __restrict__ sord, int n)
{
  long i = (long)blockIdx.x*256 + threadIdx.x;
  if (i < n){ maxb[i] = NEG_MAX_ORD; den[i] = 0.f; }
  if (i < (long)n*HSZ){
    acc[i] = 0.f;
    if (sord) sord[i] = NEG_MAX_ORD;
  }
}

__global__ void edge_max(const int* __restrict__ src, const int* __restrict__ dst,
                         const float* __restrict__ es, const float* __restrict__ ed,
                         unsigned* __restrict__ maxb, int E, int n)
{
  int i = blockIdx.x*256 + threadIdx.x;
  if (i >= E + n) return;
  int s, d;
  if (i < E){ s = src[i]; d = dst[i]; } else { s = d = i - E; }
  float e = es[s] + ed[d];
  e = e > 0.f ? e : 0.2f*e;
  atomicMax(maxb + d, fordu(e));
}

__global__ void edge_sum(const int* __restrict__ src, const int* __restrict__ dst,
                         const float* __restrict__ es, const float* __restrict__ ed,
                         const unsigned* __restrict__ maxb, float* __restrict__ den,
                         float* __restrict__ wbuf, int E, int n)
{
  int i = blockIdx.x*256 + threadIdx.x;
  if (i >= E + n) return;
  int s, d;
  if (i < E){ s = src[i]; d = dst[i]; } else { s = d = i - E; }
  float e = es[s] + ed[d];
  e = e > 0.f ? e : 0.2f*e;
  float w = __expf(e - unfordu(maxb[d]));
  wbuf[i] = w;
  atomicAdd(den + d, w);
}

__global__ void edge_scatter(const int* __restrict__ src, const int* __restrict__ dst,
                             const float* __restrict__ wbuf, const float* __restrict__ den,
                             const float* __restrict__ Hv, float* __restrict__ acc,
                             int E, int n)
{
  long t = (long)blockIdx.x*256 + threadIdx.x;
  long i = t >> 5;
  int  j = (int)(t & 31);
  if (i >= E + n) return;
  int s, d;
  if (i < E){ s = src[i]; d = dst[i]; } else { s = d = (int)(i - E); }
  float alpha = wbuf[i] / den[d];
  float4 hv = ((const float4*)(Hv + (long)s*HSZ))[j];
  float* o = acc + (long)d*HSZ + j*4;
  atomicAdd(o+0, alpha*hv.x);
  atomicAdd(o+1, alpha*hv.y);
  atomicAdd(o+2, alpha*hv.z);
  atomicAdd(o+3, alpha*hv.w);
}

__global__ void bias_pool(float* __restrict__ acc, const float* __restrict__ bias,
                          const int* __restrict__ sid, unsigned* __restrict__ sord, int n)
{
  long i = (long)blockIdx.x*256 + threadIdx.x;
  if (i >= (long)n*HSZ) return;
  int row = (int)(i >> 7), d = (int)(i & 127);
  float v = acc[i] + bias[d];
  acc[i] = v;
  atomicMax(sord + sid[row]*HSZ + d, fordu(v));
}

__global__ void pool_decode(const unsigned* __restrict__ sord, float* __restrict__ spool)
{
  int i = blockIdx.x*256 + threadIdx.x;
  spool[i] = unfordu(sord[i]);
}

__global__ void inter_bias_k(const float* __restrict__ acc2, const float* __restrict__ bias,
                             float* __restrict__ isec)
{
  int i = blockIdx.x*256 + threadIdx.x;
  isec[i] = acc2[i] + bias[i & 127];
}

__global__ __launch_bounds__(256)
void fusion_k(const float* __restrict__ seq, const float* __restrict__ intra,
              const float* __restrict__ isec, const int* __restrict__ sid,
              const float* __restrict__ fw, const float* __restrict__ fb,
              float* __restrict__ out, int n)
{
  int i = blockIdx.x*4 + (threadIdx.x >> 6);
  int l = threadIdx.x & 63;
  if (i >= n) return;
  int sc = sid[i];
  long b = (long)i*HSZ;
  long sb = (long)sc*HSZ;
  float acc = fw[l]     * seq[b + l]      + fw[64 + l]  * seq[b + 64 + l]
            + fw[128+l] * intra[b + l]    + fw[192 + l] * intra[b + 64 + l]
            + fw[256+l] * isec[sb + l]    + fw[320 + l] * isec[sb + 64 + l];
  #pragma unroll
  for (int m = 1; m < 64; m <<= 1) acc += __shfl_xor(acc, m, 64);
  if (l == 0) out[i] = acc + fb[0];
}

extern "C" void kernel_launch(void* const* d_in, const int* in_sizes, int n_in,
                              void* d_out, int out_size, void* d_ws, size_t ws_size,
                              hipStream_t stream)
{
  const float* x    = (const float*)d_in[0];
  const int*   iei  = (const int*)d_in[1];
  const int*   eei  = (const int*)d_in[2];
  const int*   sid  = (const int*)d_in[3];
  const float* wih0 = (const float*)d_in[4];
  const float* whh0 = (const float*)d_in[5];
  const float* bih0 = (const float*)d_in[6];
  const float* bhh0 = (const float*)d_in[7];
  const float* wih1 = (const float*)d_in[8];
  const float* whh1 = (const float*)d_in[9];
  const float* bih1 = (const float*)d_in[10];
  const float* bhh1 = (const float*)d_in[11];
  const float* iW   = (const float*)d_in[12];
  const float* ias  = (const float*)d_in[13];
  const float* iad  = (const float*)d_in[14];
  const float* ib   = (const float*)d_in[15];
  const float* eW   = (const float*)d_in[16];
  const float* eas  = (const float*)d_in[17];
  const float* ead  = (const float*)d_in[18];
  const float* eb   = (const float*)d_in[19];
  const float* fW   = (const float*)d_in[20];
  const float* fb   = (const float*)d_in[21];

  float* ws = (float*)d_ws;
  const long avail = (long)(ws_size / 4);

  // pick time-window Tw so gi/out0 window buffers fit workspace
  int Tw = 0;
  for (int cand = 8; cand >= 1; cand >>= 1){
    if (10240000L*cand + 11025376L <= avail){ Tw = cand; break; }
  }

  const float* seq = nullptr;
  float *hintra, *acc, *es, *ed, *den, *wbf, *spool, *hinter, *acc2;
  float *es2, *ed2, *den2, *wbf2, *isec;
  unsigned *mx, *sord, *mx2;

  if (Tw > 0){
    long off = 0;
    float* h0s   = ws + off; off += 2560000;
    float* h1s   = ws + off; off += 2560000;        // final = seq_emb
    float* giW   = ws + off; off += 20000L*Tw*384;
    float* out0W = ws + off; off += 20000L*Tw*128;
    hintra = ws + off; off += 2560000;
    acc    = ws + off; off += 2560000;
    es  = ws + off; off += 20000;
    ed  = ws + off; off += 20000;
    mx  = (unsigned*)(ws + off); off += 20000;
    den = ws + off; off += 20000;
    wbf = ws + off; off += 660000;
    sord  = (unsigned*)(ws + off); off += 8192;
    spool = ws + off; off += 8192;
    hinter= ws + off; off += 8192;
    acc2  = ws + off; off += 8192;
    es2 = ws + off; off += 64;
    ed2 = ws + off; off += 64;
    mx2 = (unsigned*)(ws + off); off += 64;
    den2= ws + off; off += 64;
    wbf2= ws + off; off += 4160;
    isec= ws + off; off += 8192;

    const int twshift = __builtin_ctz(Tw);
    const int tiles   = 250*Tw;          // (20000*Tw)/80
    const int NW      = 32/Tw;
    for (int w = 0; w < NW; ++w){
      const int t0 = w*Tw;
      gi_gemm64 <<<tiles, 384, 0, stream>>>(x,     wih0, bih0, giW, twshift, t0, 2048L,        tiles);
      gru_rec   <<<500,   384, 0, stream>>>(giW, whh0, bhh0, h0s, out0W, Tw, t0);
      gi_gemm128<<<tiles, 384, 0, stream>>>(out0W, wih1, bih1, giW, twshift, 0, (long)Tw*128, tiles);
      gru_rec   <<<500,   384, 0, stream>>>(giW, whh1, bhh1, h1s, nullptr, Tw, t0);
    }
    seq = h1s;
  } else {
    long off = 0;
    float* seqb = ws + off; off += 2560000;
    hintra = ws + off; off += 2560000;
    acc    = ws + off; off += 2560000;
    es  = ws + off; off += 20000;
    ed  = ws + off; off += 20000;
    mx  = (unsigned*)(ws + off); off += 20000;
    den = ws + off; off += 20000;
    wbf = ws + off; off += 660000;
    sord  = (unsigned*)(ws + off); off += 8192;
    spool = ws + off; off += 8192;
    hinter= ws + off; off += 8192;
    acc2  = ws + off; off += 8192;
    es2 = ws + off; off += 64;
    ed2 = ws + off; off += 64;
    mx2 = (unsigned*)(ws + off); off += 64;
    den2= ws + off; off += 64;
    wbf2= ws + off; off += 4160;
    isec= ws + off; off += 8192;

    gru2_fused<<<625, 256, 0, stream>>>(x, wih0, whh0, bih0, bhh0,
                                        wih1, whh1, bih1, bhh1, seqb);
    seq = seqb;
  }

  // ---- GAT stage ----
  gat_transform<<<313, 256, 0, stream>>>(seq, iW, ias, iad, hintra, es, ed, NCOMP);
  gat_init<<<10000, 256, 0, stream>>>(mx, den, acc, nullptr, NCOMP);
  gat_init<<<32, 256, 0, stream>>>(mx2, den2, acc2, sord, NSEC);
  {
    int tot = EINTRA + NCOMP;
    edge_max    <<<(tot+255)/256, 256, 0, stream>>>(iei, iei+EINTRA, es, ed, mx, EINTRA, NCOMP);
    edge_sum    <<<(tot+255)/256, 256, 0, stream>>>(iei, iei+EINTRA, es, ed, mx, den, wbf, EINTRA, NCOMP);
    edge_scatter<<<(int)(((long)tot*32)/256), 256, 0, stream>>>(iei, iei+EINTRA, wbf, den, hintra, acc, EINTRA, NCOMP);
  }
  bias_pool<<<10000, 256, 0, stream>>>(acc, ib, sid, sord, NCOMP);
  pool_decode<<<32, 256, 0, stream>>>(sord, spool);

  gat_transform<<<1, 256, 0, stream>>>(spool, eW, eas, ead, hinter, es2, ed2, NSEC);
  {
    int tot = EINTER + NSEC;
    edge_max    <<<(tot+255)/256, 256, 0, stream>>>(eei, eei+EINTER, es2, ed2, mx2, EINTER, NSEC);
    edge_sum    <<<(tot+255)/256, 256, 0, stream>>>(eei, eei+EINTER, es2, ed2, mx2, den2, wbf2, EINTER, NSEC);
    edge_scatter<<<(tot*32)/256, 256, 0, stream>>>(eei, eei+EINTER, wbf2, den2, hinter, acc2, EINTER, NSEC);
  }
  inter_bias_k<<<32, 256, 0, stream>>>(acc2, eb, isec);

  fusion_k<<<5000, 256, 0, stream>>>(seq, acc, isec, sid, fW, fb, (float*)d_out, NCOMP);
}

// Round 4
// 11577.975 us; speedup vs baseline: 5.2457x; 1.0886x over previous
//
#include <hip/hip_runtime.h>
#include <math.h>

// Problem constants
#define NCOMP 20000
#define SEQT  32
#define INSZ  64
#define HSZ   128
#define EINTRA 640000
#define EINTER 4096
#define NSEC  64

#define LDH 132   // padded LDS row stride (floats) for gat_transform

__device__ __forceinline__ float dot4f(float4 a, float4 b){
  return a.x*b.x + a.y*b.y + a.z*b.z + a.w*b.w;
}
__device__ __forceinline__ float sigm(float x){ return 1.f/(1.f + __expf(-x)); }
__device__ __forceinline__ float ftanh(float x){
  float cx = fminf(fmaxf(x, -15.f), 15.f);
  float e = __expf(2.f*cx);
  return (e - 1.f)/(e + 1.f);
}
// monotone float<->uint mapping so atomicMax works for signed floats (inter path)
__device__ __forceinline__ unsigned fordu(float f){
  unsigned b = __float_as_uint(f);
  return (b & 0x80000000u) ? ~b : (b | 0x80000000u);
}
__device__ __forceinline__ float unfordu(unsigned u){
  unsigned b = (u & 0x80000000u) ? (u & 0x7fffffffu) : ~u;
  return __uint_as_float(b);
}
#define NEG_MAX_ORD 0x00800000u   // fordu(-FLT_MAX)

// ===========================================================================
// FUSED 2-LAYER GRU, single dispatch.
// Block = 40 companies (4 waves x 10). Wave-private h0/h1 rows in LDS ->
// ZERO __syncthreads in the t-loop (intra-wave lgkmcnt ordering suffices).
// Per (layer, t): ONE merged GEMM N=384 (r|z|n gates), register tile
// TM=5 x TN=12, A(h) from LDS (5 ds_read_b128 per 240 FMA-instr), B(weights)
// streamed from global/L2. n-gate keeps separate x-part / h-part accumulators
// (n = tanh(gin + r*hgn)). Elementwise is fully thread-local.
// LDS 42.2 KB -> 2 blocks/CU (8 waves). 500 blocks = one full round.
// ===========================================================================
__device__ __forceinline__ void gemm3(
    float arz[5][8], float an[5][4],
    const float4* __restrict__ A, int astr,   // A[i*astr + k4], i = 0..4
    const float4* __restrict__ W, int wstr,   // W[col*wstr + k4]
    int gg, int k4len)
{
  for (int k4 = 0; k4 < k4len; ++k4){
    float4 a0 = A[0*astr + k4];
    float4 a1 = A[1*astr + k4];
    float4 a2 = A[2*astr + k4];
    float4 a3 = A[3*astr + k4];
    float4 a4 = A[4*astr + k4];
    #pragma unroll
    for (int cc = 0; cc < 8; ++cc){
      int col = (cc < 4) ? (gg*4 + cc) : (124 + gg*4 + cc);  // r: d, z: 128+d
      float4 b = W[col*wstr + k4];
      arz[0][cc] += dot4f(a0, b);
      arz[1][cc] += dot4f(a1, b);
      arz[2][cc] += dot4f(a2, b);
      arz[3][cc] += dot4f(a3, b);
      arz[4][cc] += dot4f(a4, b);
    }
    #pragma unroll
    for (int jj = 0; jj < 4; ++jj){
      int col = 256 + gg*4 + jj;                             // n: 256+d
      float4 b = W[col*wstr + k4];
      an[0][jj] += dot4f(a0, b);
      an[1][jj] += dot4f(a1, b);
      an[2][jj] += dot4f(a2, b);
      an[3][jj] += dot4f(a3, b);
      an[4][jj] += dot4f(a4, b);
    }
  }
}

__global__ __launch_bounds__(256, 2)
void gru_fused(const float* __restrict__ x,
               const float* __restrict__ wih0, const float* __restrict__ whh0,
               const float* __restrict__ bih0, const float* __restrict__ bhh0,
               const float* __restrict__ wih1, const float* __restrict__ whh1,
               const float* __restrict__ bih1, const float* __restrict__ bhh1,
               float* __restrict__ seq)
{
  __shared__ float4 h0s[40*33];   // 10 rows per wave, 33 float4/row (128 + pad)
  __shared__ float4 h1s[40*33];
  const int tid  = threadIdx.x;
  const int wave = tid >> 6, lane = tid & 63;
  const int mg2  = lane >> 5, gg = lane & 31;
  const int wrow = wave*10 + mg2*5;      // block-local first company row
  const int c0   = blockIdx.x*40;

  // zero this wave's h rows (incl. pad)
  {
    float4 z4 = make_float4(0.f,0.f,0.f,0.f);
    for (int idx = lane; idx < 330; idx += 64){
      int r = idx/33, c = idx - r*33;
      h0s[(wave*10 + r)*33 + c] = z4;
      h1s[(wave*10 + r)*33 + c] = z4;
    }
  }

  // per-thread gate-column biases (cols gg*4..+3 of each gate)
  float brz0[8], bnx0[4], bnh0[4], brz1[8], bnx1[4], bnh1[4];
  #pragma unroll
  for (int jj = 0; jj < 4; ++jj){
    int c = gg*4 + jj;
    brz0[jj]   = bih0[c]     + bhh0[c];
    brz0[4+jj] = bih0[128+c] + bhh0[128+c];
    bnx0[jj]   = bih0[256+c];
    bnh0[jj]   = bhh0[256+c];
    brz1[jj]   = bih1[c]     + bhh1[c];
    brz1[4+jj] = bih1[128+c] + bhh1[128+c];
    bnx1[jj]   = bih1[256+c];
    bnh1[jj]   = bhh1[256+c];
  }

  const float4* x4    = (const float4*)x;
  const float4* wih04 = (const float4*)wih0;
  const float4* whh04 = (const float4*)whh0;
  const float4* wih14 = (const float4*)wih1;
  const float4* whh14 = (const float4*)whh1;
  float4* Ah0 = h0s + wrow*33;
  float4* Ah1 = h1s + wrow*33;
  const float4* Ax_base = x4 + (size_t)(c0 + wrow)*512;   // row stride 512 float4

  for (int t = 0; t < SEQT; ++t){
    // ---------------- layer 0 ----------------
    float arz[5][8], anx[5][4], anh[5][4];
    #pragma unroll
    for (int i = 0; i < 5; ++i){
      #pragma unroll
      for (int cc = 0; cc < 8; ++cc) arz[i][cc] = brz0[cc];
      #pragma unroll
      for (int jj = 0; jj < 4; ++jj){ anx[i][jj] = bnx0[jj]; anh[i][jj] = bnh0[jj]; }
    }
    gemm3(arz, anx, Ax_base + t*16, 512, wih04, 16, gg, 16);  // x part, K=64
    gemm3(arz, anh, Ah0,            33,  whh04, 32, gg, 32);  // h part, K=128
    #pragma unroll
    for (int i = 0; i < 5; ++i){
      float4 hold = Ah0[i*33 + gg];
      float4 hn;
      { float r=sigm(arz[i][0]), z=sigm(arz[i][4]);
        float n=ftanh(anx[i][0]+r*anh[i][0]); hn.x=(1.f-z)*n+z*hold.x; }
      { float r=sigm(arz[i][1]), z=sigm(arz[i][5]);
        float n=ftanh(anx[i][1]+r*anh[i][1]); hn.y=(1.f-z)*n+z*hold.y; }
      { float r=sigm(arz[i][2]), z=sigm(arz[i][6]);
        float n=ftanh(anx[i][2]+r*anh[i][2]); hn.z=(1.f-z)*n+z*hold.z; }
      { float r=sigm(arz[i][3]), z=sigm(arz[i][7]);
        float n=ftanh(anx[i][3]+r*anh[i][3]); hn.w=(1.f-z)*n+z*hold.w; }
      Ah0[i*33 + gg] = hn;
    }
    // ---------------- layer 1 ----------------
    #pragma unroll
    for (int i = 0; i < 5; ++i){
      #pragma unroll
      for (int cc = 0; cc < 8; ++cc) arz[i][cc] = brz1[cc];
      #pragma unroll
      for (int jj = 0; jj < 4; ++jj){ anx[i][jj] = bnx1[jj]; anh[i][jj] = bnh1[jj]; }
    }
    gemm3(arz, anx, Ah0, 33, wih14, 32, gg, 32);  // input = new h0, K=128
    gemm3(arz, anh, Ah1, 33, whh14, 32, gg, 32);  // hidden h1, K=128
    #pragma unroll
    for (int i = 0; i < 5; ++i){
      float4 hold = Ah1[i*33 + gg];
      float4 hn;
      { float r=sigm(arz[i][0]), z=sigm(arz[i][4]);
        float n=ftanh(anx[i][0]+r*anh[i][0]); hn.x=(1.f-z)*n+z*hold.x; }
      { float r=sigm(arz[i][1]), z=sigm(arz[i][5]);
        float n=ftanh(anx[i][1]+r*anh[i][1]); hn.y=(1.f-z)*n+z*hold.y; }
      { float r=sigm(arz[i][2]), z=sigm(arz[i][6]);
        float n=ftanh(anx[i][2]+r*anh[i][2]); hn.z=(1.f-z)*n+z*hold.z; }
      { float r=sigm(arz[i][3]), z=sigm(arz[i][7]);
        float n=ftanh(anx[i][3]+r*anh[i][3]); hn.w=(1.f-z)*n+z*hold.w; }
      Ah1[i*33 + gg] = hn;
      if (t == SEQT-1)
        ((float4*)seq)[(size_t)(c0 + wrow + i)*32 + gg] = hn;
    }
  }
}

// ===========================================================================
// GAT stage — CSR build + atomic-free per-node gather
// ===========================================================================
__global__ __launch_bounds__(256)
void gat_transform(const float* __restrict__ X, const float* __restrict__ W,
                   const float* __restrict__ asrc, const float* __restrict__ adst,
                   float* __restrict__ Hout, float* __restrict__ es, float* __restrict__ ed,
                   int n)
{
  __shared__ float sX[64*LDH];
  const int tid = threadIdx.x;
  const long base = (long)blockIdx.x * 64;
  for (int i = tid; i < 64*32; i += 256){
    int row = i >> 5, q = i & 31;
    long gr = base + row;
    float4 v = make_float4(0.f, 0.f, 0.f, 0.f);
    if (gr < n) v = ((const float4*)(X + gr*HSZ))[q];
    ((float4*)(sX + row*LDH))[q] = v;
  }
  __syncthreads();
  const int rp = tid >> 3, dg = tid & 7;
  const int r0 = rp*2, r1 = r0 + 1;
  const float4* xa = (const float4*)(sX + r0*LDH);
  const float4* xb = (const float4*)(sX + r1*LDH);
  float ps0=0.f, pd0=0.f, ps1=0.f, pd1=0.f;
  for (int dd = 0; dd < 16; ++dd){
    const int cidx = dg*16 + dd;
    const float4* wp = (const float4*)(W + cidx*HSZ);
    float a0 = 0.f, a1 = 0.f;
    #pragma unroll 4
    for (int q = 0; q < 32; ++q){
      float4 w = wp[q];
      a0 += dot4f(w, xa[q]);
      a1 += dot4f(w, xb[q]);
    }
    float s = asrc[cidx], dv = adst[cidx];
    ps0 += a0*s; pd0 += a0*dv;
    ps1 += a1*s; pd1 += a1*dv;
    if (base + r0 < n) Hout[(base+r0)*HSZ + cidx] = a0;
    if (base + r1 < n) Hout[(base+r1)*HSZ + cidx] = a1;
  }
  #pragma unroll
  for (int m = 1; m < 8; m <<= 1){
    ps0 += __shfl_xor(ps0, m, 64);
    pd0 += __shfl_xor(pd0, m, 64);
    ps1 += __shfl_xor(ps1, m, 64);
    pd1 += __shfl_xor(pd1, m, 64);
  }
  if (dg == 0){
    if (base + r0 < n){ es[base+r0] = ps0; ed[base+r0] = pd0; }
    if (base + r1 < n){ es[base+r1] = ps1; ed[base+r1] = pd1; }
  }
}

__global__ void zero_i(int* __restrict__ p, int n)
{
  int i = blockIdx.x*256 + threadIdx.x;
  if (i < n) p[i] = 0;
}

__global__ void csr_count(const int* __restrict__ dst, int* __restrict__ cnt, int E)
{
  int i = blockIdx.x*256 + threadIdx.x;
  if (i < E) atomicAdd(&cnt[dst[i]], 1);
}

// single block, 1024 threads: exclusive scan of cnt[0..n) -> rowptr, cursor
__global__ __launch_bounds__(1024)
void csr_scan(const int* __restrict__ cnt, int* __restrict__ rowptr,
              int* __restrict__ cursor, int n)
{
  __shared__ int ls[1024];
  const int t = threadIdx.x;
  const int base = t*20;
  int loc[20];
  int s = 0;
  #pragma unroll
  for (int k = 0; k < 20; ++k){
    int idx = base + k;
    int v = (idx < n) ? cnt[idx] : 0;
    loc[k] = s; s += v;
  }
  ls[t] = s;
  __syncthreads();
  for (int off = 1; off < 1024; off <<= 1){
    int v = (t >= off) ? ls[t-off] : 0;
    __syncthreads();
    ls[t] += v;
    __syncthreads();
  }
  int excl = (t == 0) ? 0 : ls[t-1];
  #pragma unroll
  for (int k = 0; k < 20; ++k){
    int idx = base + k;
    if (idx < n){ int rp = excl + loc[k]; rowptr[idx] = rp; cursor[idx] = rp; }
  }
  if (t == 1023) rowptr[n] = ls[1023];
}

__global__ void csr_fill(const int* __restrict__ src, const int* __restrict__ dst,
                         int* __restrict__ cursor, int* __restrict__ csrc, int E)
{
  int i = blockIdx.x*256 + threadIdx.x;
  if (i >= E) return;
  int p = atomicAdd(&cursor[dst[i]], 1);
  csrc[p] = src[i];
}

// one wave per destination node: leaky-relu logits, online max, denom, then
// weighted gather of Hv rows. Self-loop included. No atomics.
__global__ __launch_bounds__(256)
void gat_gather(const int* __restrict__ rowptr, const int* __restrict__ csrc,
                const float* __restrict__ es, const float* __restrict__ ed,
                const float* __restrict__ Hv, const float* __restrict__ bias,
                float* __restrict__ out, int n)
{
  int d = blockIdx.x*4 + (threadIdx.x >> 6);
  int l = threadIdx.x & 63;
  if (d >= n) return;
  const int p0 = rowptr[d], p1 = rowptr[d+1];
  const float edd = ed[d];
  float eself = es[d] + edd;
  eself = eself > 0.f ? eself : 0.2f*eself;
  // pass 1: max
  float m = eself;
  for (int j = p0 + l; j < p1; j += 64){
    int s = csrc[j];
    float e = es[s] + edd;
    e = e > 0.f ? e : 0.2f*e;
    m = fmaxf(m, e);
  }
  #pragma unroll
  for (int off = 1; off < 64; off <<= 1) m = fmaxf(m, __shfl_xor(m, off, 64));
  // pass 2: denom
  float part = 0.f;
  for (int j = p0 + l; j < p1; j += 64){
    int s = csrc[j];
    float e = es[s] + edd;
    e = e > 0.f ? e : 0.2f*e;
    part += __expf(e - m);
  }
  #pragma unroll
  for (int off = 1; off < 64; off <<= 1) part += __shfl_xor(part, off, 64);
  const float wself = __expf(eself - m);
  const float inv = 1.f/(part + wself);
  // pass 3: weighted gather (serial over edges, lanes parallel over dims)
  float a = wself*inv;
  float acc0 = a * Hv[(long)d*HSZ + l];
  float acc1 = a * Hv[(long)d*HSZ + 64 + l];
  for (int j = p0; j < p1; ++j){
    int s = csrc[j];
    float e = es[s] + edd;
    e = e > 0.f ? e : 0.2f*e;
    float al = __expf(e - m)*inv;
    acc0 += al * Hv[(long)s*HSZ + l];
    acc1 += al * Hv[(long)s*HSZ + 64 + l];
  }
  out[(long)d*HSZ + l]      = acc0 + bias[l];
  out[(long)d*HSZ + 64 + l] = acc1 + bias[64 + l];
}

// per-sector max pool: one block per sector scans all rows (no atomics)
__global__ __launch_bounds__(256)
void sector_pool(const float* __restrict__ intra, const int* __restrict__ sid,
                 float* __restrict__ spool, int n)
{
  const int sec = blockIdx.x;
  const int t = threadIdx.x;
  const int d = t & 127, half = t >> 7;
  float m = -3.402823466e+38f;
  for (int r = half; r < n; r += 2){
    if (sid[r] == sec) m = fmaxf(m, intra[(long)r*HSZ + d]);
  }
  __shared__ float red[256];
  red[t] = m;
  __syncthreads();
  if (half == 0) spool[sec*HSZ + d] = fmaxf(red[d], red[128 + d]);
}

// ---- inter-sector GAT (tiny, keep atomic path) ----
__global__ void gat_init(unsigned* __restrict__ maxb, float* __restrict__ den,
                         float* __restrict__ acc, unsigned* __restrict__ sord, int n)
{
  long i = (long)blockIdx.x*256 + threadIdx.x;
  if (i < n){ maxb[i] = NEG_MAX_ORD; den[i] = 0.f; }
  if (i < (long)n*HSZ){
    acc[i] = 0.f;
    if (sord) sord[i] = NEG_MAX_ORD;
  }
}

__global__ void edge_max(const int* __restrict__ src, const int* __restrict__ dst,
                         const float* __restrict__ es, const float* __restrict__ ed,
                         unsigned* __restrict__ maxb, int E, int n)
{
  int i = blockIdx.x*256 + threadIdx.x;
  if (i >= E + n) return;
  int s, d;
  if (i < E){ s = src[i]; d = dst[i]; } else { s = d = i - E; }
  float e = es[s] + ed[d];
  e = e > 0.f ? e : 0.2f*e;
  atomicMax(maxb + d, fordu(e));
}

__global__ void edge_sum(const int* __restrict__ src, const int* __restrict__ dst,
                         const float* __restrict__ es, const float* __restrict__ ed,
                         const unsigned* __restrict__ maxb, float* __restrict__ den,
                         float* __restrict__ wbuf, int E, int n)
{
  int i = blockIdx.x*256 + threadIdx.x;
  if (i >= E + n) return;
  int s, d;
  if (i < E){ s = src[i]; d = dst[i]; } else { s = d = i - E; }
  float e = es[s] + ed[d];
  e = e > 0.f ? e : 0.2f*e;
  float w = __expf(e - unfordu(maxb[d]));
  wbuf[i] = w;
  atomicAdd(den + d, w);
}

__global__ void edge_scatter(const int* __restrict__ src, const int* __restrict__ dst,
                             const float* __restrict__ wbuf, const float* __restrict__ den,
                             const float* __restrict__ Hv, float* __restrict__ acc,
                             int E, int n)
{
  long t = (long)blockIdx.x*256 + threadIdx.x;
  long i = t >> 5;
  int  j = (int)(t & 31);
  if (i >= E + n) return;
  int s, d;
  if (i < E){ s = src[i]; d = dst[i]; } else { s = d = (int)(i - E); }
  float alpha = wbuf[i] / den[d];
  float4 hv = ((const float4*)(Hv + (long)s*HSZ))[j];
  float* o = acc + (long)d*HSZ + j*4;
  atomicAdd(o+0, alpha*hv.x);
  atomicAdd(o+1, alpha*hv.y);
  atomicAdd(o+2, alpha*hv.z);
  atomicAdd(o+3, alpha*hv.w);
}

__global__ void inter_bias_k(const float* __restrict__ acc2, const float* __restrict__ bias,
                             float* __restrict__ isec)
{
  int i = blockIdx.x*256 + threadIdx.x;   // exactly 64*128
  isec[i] = acc2[i] + bias[i & 127];
}

__global__ __launch_bounds__(256)
void fusion_k(const float* __restrict__ seq, const float* __restrict__ intra,
              const float* __restrict__ isec, const int* __restrict__ sid,
              const float* __restrict__ fw, const float* __restrict__ fb,
              float* __restrict__ out, int n)
{
  int i = blockIdx.x*4 + (threadIdx.x >> 6);
  int l = threadIdx.x & 63;
  if (i >= n) return;
  int sc = sid[i];
  long b = (long)i*HSZ;
  long sb = (long)sc*HSZ;
  float acc = fw[l]     * seq[b + l]      + fw[64 + l]  * seq[b + 64 + l]
            + fw[128+l] * intra[b + l]    + fw[192 + l] * intra[b + 64 + l]
            + fw[256+l] * isec[sb + l]    + fw[320 + l] * isec[sb + 64 + l];
  #pragma unroll
  for (int m = 1; m < 64; m <<= 1) acc += __shfl_xor(acc, m, 64);
  if (l == 0) out[i] = acc + fb[0];
}

extern "C" void kernel_launch(void* const* d_in, const int* in_sizes, int n_in,
                              void* d_out, int out_size, void* d_ws, size_t ws_size,
                              hipStream_t stream)
{
  const float* x    = (const float*)d_in[0];
  const int*   iei  = (const int*)d_in[1];    // [2, 640000]
  const int*   eei  = (const int*)d_in[2];    // [2, 4096]
  const int*   sid  = (const int*)d_in[3];
  const float* wih0 = (const float*)d_in[4];
  const float* whh0 = (const float*)d_in[5];
  const float* bih0 = (const float*)d_in[6];
  const float* bhh0 = (const float*)d_in[7];
  const float* wih1 = (const float*)d_in[8];
  const float* whh1 = (const float*)d_in[9];
  const float* bih1 = (const float*)d_in[10];
  const float* bhh1 = (const float*)d_in[11];
  const float* iW   = (const float*)d_in[12];
  const float* ias  = (const float*)d_in[13];
  const float* iad  = (const float*)d_in[14];
  const float* ib   = (const float*)d_in[15];
  const float* eW   = (const float*)d_in[16];
  const float* eas  = (const float*)d_in[17];
  const float* ead  = (const float*)d_in[18];
  const float* eb   = (const float*)d_in[19];
  const float* fW   = (const float*)d_in[20];
  const float* fb   = (const float*)d_in[21];

  float* ws = (float*)d_ws;
  long off = 0;
  float* seq    = ws + off; off += 2560000;
  float* hintra = ws + off; off += 2560000;
  float* intra  = ws + off; off += 2560000;
  float* es     = ws + off; off += 20000;
  float* ed     = ws + off; off += 20000;
  int*   cnt    = (int*)(ws + off); off += 20000;
  int*   rowptr = (int*)(ws + off); off += 20004;
  int*   cursor = (int*)(ws + off); off += 20000;
  int*   csrc   = (int*)(ws + off); off += 640000;
  float* spool  = ws + off; off += 8192;
  float* hinter = ws + off; off += 8192;
  float* acc2   = ws + off; off += 8192;
  float* es2    = ws + off; off += 64;
  float* ed2    = ws + off; off += 64;
  unsigned* mx2 = (unsigned*)(ws + off); off += 64;
  float* den2   = ws + off; off += 64;
  float* wbf2   = ws + off; off += 4160;
  float* isec   = ws + off; off += 8192;
  // total ~8.43M floats = ~34 MB (well within the R2/R3-proven workspace)

  // 1) fused 2-layer GRU -> seq_emb  (one dispatch)
  gru_fused<<<500, 256, 0, stream>>>(x, wih0, whh0, bih0, bhh0,
                                     wih1, whh1, bih1, bhh1, seq);

  // 2) intra GAT: transform + CSR build + atomic-free gather
  gat_transform<<<313, 256, 0, stream>>>(seq, iW, ias, iad, hintra, es, ed, NCOMP);
  zero_i   <<<(NCOMP+255)/256, 256, 0, stream>>>(cnt, NCOMP);
  csr_count<<<(EINTRA+255)/256, 256, 0, stream>>>(iei + EINTRA, cnt, EINTRA);
  csr_scan <<<1, 1024, 0, stream>>>(cnt, rowptr, cursor, NCOMP);
  csr_fill <<<(EINTRA+255)/256, 256, 0, stream>>>(iei, iei + EINTRA, cursor, csrc, EINTRA);
  gat_gather<<<NCOMP/4, 256, 0, stream>>>(rowptr, csrc, es, ed, hintra, ib, intra, NCOMP);

  // 3) per-sector max pool (scan, no atomics)
  sector_pool<<<NSEC, 256, 0, stream>>>(intra, sid, spool, NCOMP);

  // 4) inter GAT (tiny: 64 nodes, 4096 edges — atomic path)
  gat_init<<<32, 256, 0, stream>>>(mx2, den2, acc2, nullptr, NSEC);
  gat_transform<<<1, 256, 0, stream>>>(spool, eW, eas, ead, hinter, es2, ed2, NSEC);
  {
    int tot = EINTER + NSEC;
    edge_max    <<<(tot+255)/256, 256, 0, stream>>>(eei, eei+EINTER, es2, ed2, mx2, EINTER, NSEC);
    edge_sum    <<<(tot+255)/256, 256, 0, stream>>>(eei, eei+EINTER, es2, ed2, mx2, den2, wbf2, EINTER, NSEC);
    edge_scatter<<<(tot*32)/256, 256, 0, stream>>>(eei, eei+EINTER, wbf2, den2, hinter, acc2, EINTER, NSEC);
  }
  inter_bias_k<<<32, 256, 0, stream>>>(acc2, eb, isec);

  // 5) fusion -> output [20000]
  fusion_k<<<NCOMP/4, 256, 0, stream>>>(seq, intra, isec, sid, fW, fb, (float*)d_out, NCOMP);
}

// Round 5
// 5332.943 us; speedup vs baseline: 11.3885x; 2.1710x over previous
//
#include <hip/hip_runtime.h>
#include <math.h>

// Problem constants
#define NCOMP 20000
#define SEQT  32
#define INSZ  64
#define HSZ   128
#define EINTRA 640000
#define EINTER 4096
#define NSEC  64

#define LDH 132   // padded LDS row stride (floats) for gat_transform

__device__ __forceinline__ float dot4f(float4 a, float4 b){
  return a.x*b.x + a.y*b.y + a.z*b.z + a.w*b.w;
}
__device__ __forceinline__ float sigm(float x){ return 1.f/(1.f + __expf(-x)); }
__device__ __forceinline__ float ftanh(float x){
  float cx = fminf(fmaxf(x, -15.f), 15.f);
  float e = __expf(2.f*cx);
  return (e - 1.f)/(e + 1.f);
}
// monotone float<->uint mapping so atomicMax works for signed floats (inter path)
__device__ __forceinline__ unsigned fordu(float f){
  unsigned b = __float_as_uint(f);
  return (b & 0x80000000u) ? ~b : (b | 0x80000000u);
}
__device__ __forceinline__ float unfordu(unsigned u){
  unsigned b = (u & 0x80000000u) ? (u & 0x7fffffffu) : ~u;
  return __uint_as_float(b);
}
#define NEG_MAX_ORD 0x00800000u   // fordu(-FLT_MAX)

// ===========================================================================
// Weight packing: Wp[k4][col] (float4 of W[col][4k4..4k4+3]), col in [0,384).
// Makes the GRU B-loads perfectly coalesced: lane l reads col l+64j -> lane
// stride 16B, 1KB/wave-instr, full cache-line utilization.
// ===========================================================================
__global__ void wpack_k(const float* __restrict__ W, float* __restrict__ Wp, int K4)
{
  int i = blockIdx.x*256 + threadIdx.x;
  if (i >= 384*K4) return;
  int k4 = i / 384, col = i - k4*384;
  int K = K4*4;
  float4 v = make_float4(W[col*K + 4*k4], W[col*K + 4*k4 + 1],
                         W[col*K + 4*k4 + 2], W[col*K + 4*k4 + 3]);
  ((float4*)Wp)[i] = v;
}

// ===========================================================================
// FUSED 2-LAYER GRU. Block = 40 companies (4 waves x 10, wave-private ->
// zero barriers in t-loop). Lane l owns output dims {l, 64+l} of all 3 gates
// (6 cols). Per k4: 10 broadcast LDS A-reads + 6 coalesced B-reads + 240 FMA.
// Weights from packed k-major layout (see wpack_k). 500 blocks, (256,2).
// ===========================================================================
__global__ __launch_bounds__(256, 2)
void gru_fused(const float* __restrict__ x,
               const float* __restrict__ w0p, const float* __restrict__ u0p,
               const float* __restrict__ bih0, const float* __restrict__ bhh0,
               const float* __restrict__ w1p, const float* __restrict__ u1p,
               const float* __restrict__ bih1, const float* __restrict__ bhh1,
               float* __restrict__ seq)
{
  __shared__ float h0s[40*128];
  __shared__ float h1s[40*128];
  const int tid  = threadIdx.x;
  const int wave = tid >> 6, l = tid & 63;
  const int wrow = wave*10;
  const int c0   = blockIdx.x*40;

  float* myh0 = h0s + wrow*128;
  float* myh1 = h1s + wrow*128;
  {
    float4 z4 = make_float4(0.f,0.f,0.f,0.f);
    for (int i = l; i < 320; i += 64){     // 10 rows x 32 float4, wave-private
      ((float4*)myh0)[i] = z4;
      ((float4*)myh1)[i] = z4;
    }
  }

  // per-thread biases for cols {l, 64+l} of each gate
  const float bR0_0 = bih0[l]      + bhh0[l];
  const float bR0_1 = bih0[64+l]   + bhh0[64+l];
  const float bZ0_0 = bih0[128+l]  + bhh0[128+l];
  const float bZ0_1 = bih0[192+l]  + bhh0[192+l];
  const float bNX0_0 = bih0[256+l],  bNX0_1 = bih0[320+l];
  const float bNH0_0 = bhh0[256+l],  bNH0_1 = bhh0[320+l];
  const float bR1_0 = bih1[l]      + bhh1[l];
  const float bR1_1 = bih1[64+l]   + bhh1[64+l];
  const float bZ1_0 = bih1[128+l]  + bhh1[128+l];
  const float bZ1_1 = bih1[192+l]  + bhh1[192+l];
  const float bNX1_0 = bih1[256+l],  bNX1_1 = bih1[320+l];
  const float bNH1_0 = bhh1[256+l],  bNH1_1 = bhh1[320+l];

  const float4* x4 = (const float4*)x;
  const float4* B0 = (const float4*)w0p;   // [16][384]
  const float4* U0 = (const float4*)u0p;   // [32][384]
  const float4* B1 = (const float4*)w1p;   // [32][384]
  const float4* U1 = (const float4*)u1p;   // [32][384]
  const float4* Ah0 = (const float4*)myh0; // row m at m*32 + k4
  const float4* Ah1 = (const float4*)myh1;

  float aR[10][2], aZ[10][2], aNX[10][2], aNH[10][2];

  #pragma unroll 1
  for (int t = 0; t < SEQT; ++t){
    // ================= layer 0 =================
    #pragma unroll
    for (int m = 0; m < 10; ++m){
      aR[m][0]=bR0_0; aR[m][1]=bR0_1; aZ[m][0]=bZ0_0; aZ[m][1]=bZ0_1;
      aNX[m][0]=bNX0_0; aNX[m][1]=bNX0_1; aNH[m][0]=bNH0_0; aNH[m][1]=bNH0_1;
    }
    // x part, K=64 (A broadcast from global, likely s_load)
    const float4* Ax = x4 + (size_t)(c0+wrow)*512 + t*16;  // row m at +m*512
    #pragma unroll 2
    for (int k4 = 0; k4 < 16; ++k4){
      float4 b0 = B0[k4*384 + l];
      float4 b1 = B0[k4*384 + 64 + l];
      float4 b2 = B0[k4*384 + 128 + l];
      float4 b3 = B0[k4*384 + 192 + l];
      float4 b4 = B0[k4*384 + 256 + l];
      float4 b5 = B0[k4*384 + 320 + l];
      #pragma unroll
      for (int m = 0; m < 10; ++m){
        float4 a = Ax[m*512 + k4];
        aR[m][0]  += dot4f(a, b0); aR[m][1]  += dot4f(a, b1);
        aZ[m][0]  += dot4f(a, b2); aZ[m][1]  += dot4f(a, b3);
        aNX[m][0] += dot4f(a, b4); aNX[m][1] += dot4f(a, b5);
      }
    }
    // h part, K=128 (A broadcast from LDS)
    #pragma unroll 2
    for (int k4 = 0; k4 < 32; ++k4){
      float4 b0 = U0[k4*384 + l];
      float4 b1 = U0[k4*384 + 64 + l];
      float4 b2 = U0[k4*384 + 128 + l];
      float4 b3 = U0[k4*384 + 192 + l];
      float4 b4 = U0[k4*384 + 256 + l];
      float4 b5 = U0[k4*384 + 320 + l];
      #pragma unroll
      for (int m = 0; m < 10; ++m){
        float4 a = Ah0[m*32 + k4];
        aR[m][0]  += dot4f(a, b0); aR[m][1]  += dot4f(a, b1);
        aZ[m][0]  += dot4f(a, b2); aZ[m][1]  += dot4f(a, b3);
        aNH[m][0] += dot4f(a, b4); aNH[m][1] += dot4f(a, b5);
      }
    }
    // elementwise -> update h0 (dims l, 64+l per company)
    #pragma unroll
    for (int m = 0; m < 10; ++m){
      float ho0 = myh0[m*128 + l], ho1 = myh0[m*128 + 64 + l];
      float r0 = sigm(aR[m][0]), z0 = sigm(aZ[m][0]);
      float n0 = ftanh(aNX[m][0] + r0*aNH[m][0]);
      float r1 = sigm(aR[m][1]), z1 = sigm(aZ[m][1]);
      float n1 = ftanh(aNX[m][1] + r1*aNH[m][1]);
      myh0[m*128 + l]      = (1.f - z0)*n0 + z0*ho0;
      myh0[m*128 + 64 + l] = (1.f - z1)*n1 + z1*ho1;
    }

    // ================= layer 1 =================
    #pragma unroll
    for (int m = 0; m < 10; ++m){
      aR[m][0]=bR1_0; aR[m][1]=bR1_1; aZ[m][0]=bZ1_0; aZ[m][1]=bZ1_1;
      aNX[m][0]=bNX1_0; aNX[m][1]=bNX1_1; aNH[m][0]=bNH1_0; aNH[m][1]=bNH1_1;
    }
    // input = new h0, K=128
    #pragma unroll 2
    for (int k4 = 0; k4 < 32; ++k4){
      float4 b0 = B1[k4*384 + l];
      float4 b1 = B1[k4*384 + 64 + l];
      float4 b2 = B1[k4*384 + 128 + l];
      float4 b3 = B1[k4*384 + 192 + l];
      float4 b4 = B1[k4*384 + 256 + l];
      float4 b5 = B1[k4*384 + 320 + l];
      #pragma unroll
      for (int m = 0; m < 10; ++m){
        float4 a = Ah0[m*32 + k4];
        aR[m][0]  += dot4f(a, b0); aR[m][1]  += dot4f(a, b1);
        aZ[m][0]  += dot4f(a, b2); aZ[m][1]  += dot4f(a, b3);
        aNX[m][0] += dot4f(a, b4); aNX[m][1] += dot4f(a, b5);
      }
    }
    // hidden h1, K=128
    #pragma unroll 2
    for (int k4 = 0; k4 < 32; ++k4){
      float4 b0 = U1[k4*384 + l];
      float4 b1 = U1[k4*384 + 64 + l];
      float4 b2 = U1[k4*384 + 128 + l];
      float4 b3 = U1[k4*384 + 192 + l];
      float4 b4 = U1[k4*384 + 256 + l];
      float4 b5 = U1[k4*384 + 320 + l];
      #pragma unroll
      for (int m = 0; m < 10; ++m){
        float4 a = Ah1[m*32 + k4];
        aR[m][0]  += dot4f(a, b0); aR[m][1]  += dot4f(a, b1);
        aZ[m][0]  += dot4f(a, b2); aZ[m][1]  += dot4f(a, b3);
        aNH[m][0] += dot4f(a, b4); aNH[m][1] += dot4f(a, b5);
      }
    }
    #pragma unroll
    for (int m = 0; m < 10; ++m){
      float ho0 = myh1[m*128 + l], ho1 = myh1[m*128 + 64 + l];
      float r0 = sigm(aR[m][0]), z0 = sigm(aZ[m][0]);
      float n0 = ftanh(aNX[m][0] + r0*aNH[m][0]);
      float r1 = sigm(aR[m][1]), z1 = sigm(aZ[m][1]);
      float n1 = ftanh(aNX[m][1] + r1*aNH[m][1]);
      float hn0 = (1.f - z0)*n0 + z0*ho0;
      float hn1 = (1.f - z1)*n1 + z1*ho1;
      myh1[m*128 + l]      = hn0;
      myh1[m*128 + 64 + l] = hn1;
      if (t == SEQT-1){
        seq[(size_t)(c0 + wrow + m)*128 + l]      = hn0;
        seq[(size_t)(c0 + wrow + m)*128 + 64 + l] = hn1;
      }
    }
  }
}

// ===========================================================================
// GAT stage — CSR build + atomic-free per-node gather
// ===========================================================================
__global__ __launch_bounds__(256)
void gat_transform(const float* __restrict__ X, const float* __restrict__ W,
                   const float* __restrict__ asrc, const float* __restrict__ adst,
                   float* __restrict__ Hout, float* __restrict__ es, float* __restrict__ ed,
                   int n)
{
  __shared__ float sX[64*LDH];
  const int tid = threadIdx.x;
  const long base = (long)blockIdx.x * 64;
  for (int i = tid; i < 64*32; i += 256){
    int row = i >> 5, q = i & 31;
    long gr = base + row;
    float4 v = make_float4(0.f, 0.f, 0.f, 0.f);
    if (gr < n) v = ((const float4*)(X + gr*HSZ))[q];
    ((float4*)(sX + row*LDH))[q] = v;
  }
  __syncthreads();
  const int rp = tid >> 3, dg = tid & 7;
  const int r0 = rp*2, r1 = r0 + 1;
  const float4* xa = (const float4*)(sX + r0*LDH);
  const float4* xb = (const float4*)(sX + r1*LDH);
  float ps0=0.f, pd0=0.f, ps1=0.f, pd1=0.f;
  for (int dd = 0; dd < 16; ++dd){
    const int cidx = dg*16 + dd;
    const float4* wp = (const float4*)(W + cidx*HSZ);
    float a0 = 0.f, a1 = 0.f;
    #pragma unroll 4
    for (int q = 0; q < 32; ++q){
      float4 w = wp[q];
      a0 += dot4f(w, xa[q]);
      a1 += dot4f(w, xb[q]);
    }
    float s = asrc[cidx], dv = adst[cidx];
    ps0 += a0*s; pd0 += a0*dv;
    ps1 += a1*s; pd1 += a1*dv;
    if (base + r0 < n) Hout[(base+r0)*HSZ + cidx] = a0;
    if (base + r1 < n) Hout[(base+r1)*HSZ + cidx] = a1;
  }
  #pragma unroll
  for (int m = 1; m < 8; m <<= 1){
    ps0 += __shfl_xor(ps0, m, 64);
    pd0 += __shfl_xor(pd0, m, 64);
    ps1 += __shfl_xor(ps1, m, 64);
    pd1 += __shfl_xor(pd1, m, 64);
  }
  if (dg == 0){
    if (base + r0 < n){ es[base+r0] = ps0; ed[base+r0] = pd0; }
    if (base + r1 < n){ es[base+r1] = ps1; ed[base+r1] = pd1; }
  }
}

__global__ void zero_i(int* __restrict__ p, int n)
{
  int i = blockIdx.x*256 + threadIdx.x;
  if (i < n) p[i] = 0;
}

__global__ void csr_count(const int* __restrict__ key, int* __restrict__ cnt, int E)
{
  int i = blockIdx.x*256 + threadIdx.x;
  if (i < E) atomicAdd(&cnt[key[i]], 1);
}

// single block, 1024 threads: exclusive scan of cnt[0..n) -> rowptr, cursor
__global__ __launch_bounds__(1024)
void csr_scan(const int* __restrict__ cnt, int* __restrict__ rowptr,
              int* __restrict__ cursor, int n)
{
  __shared__ int ls[1024];
  const int t = threadIdx.x;
  const int base = t*20;
  int loc[20];
  int s = 0;
  #pragma unroll
  for (int k = 0; k < 20; ++k){
    int idx = base + k;
    int v = (idx < n) ? cnt[idx] : 0;
    loc[k] = s; s += v;
  }
  ls[t] = s;
  __syncthreads();
  for (int off = 1; off < 1024; off <<= 1){
    int v = (t >= off) ? ls[t-off] : 0;
    __syncthreads();
    ls[t] += v;
    __syncthreads();
  }
  int excl = (t == 0) ? 0 : ls[t-1];
  #pragma unroll
  for (int k = 0; k < 20; ++k){
    int idx = base + k;
    if (idx < n){ int rp = excl + loc[k]; rowptr[idx] = rp; cursor[idx] = rp; }
  }
  if (t == 1023) rowptr[n] = ls[1023];
}

// val==nullptr -> store the element index i (used for sector row lists)
__global__ void csr_fill(const int* __restrict__ val, const int* __restrict__ key,
                         int* __restrict__ cursor, int* __restrict__ outl, int E)
{
  int i = blockIdx.x*256 + threadIdx.x;
  if (i >= E) return;
  int p = atomicAdd(&cursor[key[i]], 1);
  outl[p] = val ? val[i] : i;
}

// one wave per destination node: leaky-relu logits, max, denom, weighted gather
__global__ __launch_bounds__(256)
void gat_gather(const int* __restrict__ rowptr, const int* __restrict__ csrc,
                const float* __restrict__ es, const float* __restrict__ ed,
                const float* __restrict__ Hv, const float* __restrict__ bias,
                float* __restrict__ out, int n)
{
  int d = blockIdx.x*4 + (threadIdx.x >> 6);
  int l = threadIdx.x & 63;
  if (d >= n) return;
  const int p0 = rowptr[d], p1 = rowptr[d+1];
  const float edd = ed[d];
  float eself = es[d] + edd;
  eself = eself > 0.f ? eself : 0.2f*eself;
  float m = eself;
  for (int j = p0 + l; j < p1; j += 64){
    int s = csrc[j];
    float e = es[s] + edd;
    e = e > 0.f ? e : 0.2f*e;
    m = fmaxf(m, e);
  }
  #pragma unroll
  for (int off = 1; off < 64; off <<= 1) m = fmaxf(m, __shfl_xor(m, off, 64));
  float part = 0.f;
  for (int j = p0 + l; j < p1; j += 64){
    int s = csrc[j];
    float e = es[s] + edd;
    e = e > 0.f ? e : 0.2f*e;
    part += __expf(e - m);
  }
  #pragma unroll
  for (int off = 1; off < 64; off <<= 1) part += __shfl_xor(part, off, 64);
  const float wself = __expf(eself - m);
  const float inv = 1.f/(part + wself);
  float a = wself*inv;
  float acc0 = a * Hv[(long)d*HSZ + l];
  float acc1 = a * Hv[(long)d*HSZ + 64 + l];
  for (int j = p0; j < p1; ++j){
    int s = csrc[j];
    float e = es[s] + edd;
    e = e > 0.f ? e : 0.2f*e;
    float al = __expf(e - m)*inv;
    acc0 += al * Hv[(long)s*HSZ + l];
    acc1 += al * Hv[(long)s*HSZ + 64 + l];
  }
  out[(long)d*HSZ + l]      = acc0 + bias[l];
  out[(long)d*HSZ + 64 + l] = acc1 + bias[64 + l];
}

// per-sector max pool using sector row-list (CSR over sid)
__global__ __launch_bounds__(256)
void sector_pool(const float* __restrict__ intra, const int* __restrict__ srowptr,
                 const int* __restrict__ slist, float* __restrict__ spool)
{
  const int sec = blockIdx.x;
  const int t = threadIdx.x;
  const int d = t & 127, half = t >> 7;
  const int p0 = srowptr[sec], p1 = srowptr[sec+1];
  float m = -3.402823466e+38f;
  for (int j = p0 + half; j < p1; j += 2){
    int r = slist[j];
    m = fmaxf(m, intra[(long)r*HSZ + d]);
  }
  __shared__ float red[256];
  red[t] = m;
  __syncthreads();
  if (half == 0) spool[sec*HSZ + d] = fmaxf(red[d], red[128 + d]);
}

// ---- inter-sector GAT (tiny, keep atomic path) ----
__global__ void gat_init(unsigned* __restrict__ maxb, float* __restrict__ den,
                         float* __restrict__ acc, int n)
{
  long i = (long)blockIdx.x*256 + threadIdx.x;
  if (i < n){ maxb[i] = NEG_MAX_ORD; den[i] = 0.f; }
  if (i < (long)n*HSZ) acc[i] = 0.f;
}

__global__ void edge_max(const int* __restrict__ src, const int* __restrict__ dst,
                         const float* __restrict__ es, const float* __restrict__ ed,
                         unsigned* __restrict__ maxb, int E, int n)
{
  int i = blockIdx.x*256 + threadIdx.x;
  if (i >= E + n) return;
  int s, d;
  if (i < E){ s = src[i]; d = dst[i]; } else { s = d = i - E; }
  float e = es[s] + ed[d];
  e = e > 0.f ? e : 0.2f*e;
  atomicMax(maxb + d, fordu(e));
}

__global__ void edge_sum(const int* __restrict__ src, const int* __restrict__ dst,
                         const float* __restrict__ es, const float* __restrict__ ed,
                         const unsigned* __restrict__ maxb, float* __restrict__ den,
                         float* __restrict__ wbuf, int E, int n)
{
  int i = blockIdx.x*256 + threadIdx.x;
  if (i >= E + n) return;
  int s, d;
  if (i < E){ s = src[i]; d = dst[i]; } else { s = d = i - E; }
  float e = es[s] + ed[d];
  e = e > 0.f ? e : 0.2f*e;
  float w = __expf(e - unfordu(maxb[d]));
  wbuf[i] = w;
  atomicAdd(den + d, w);
}

__global__ void edge_scatter(const int* __restrict__ src, const int* __restrict__ dst,
                             const float* __restrict__ wbuf, const float* __restrict__ den,
                             const float* __restrict__ Hv, float* __restrict__ acc,
                             int E, int n)
{
  long t = (long)blockIdx.x*256 + threadIdx.x;
  long i = t >> 5;
  int  j = (int)(t & 31);
  if (i >= E + n) return;
  int s, d;
  if (i < E){ s = src[i]; d = dst[i]; } else { s = d = (int)(i - E); }
  float alpha = wbuf[i] / den[d];
  float4 hv = ((const float4*)(Hv + (long)s*HSZ))[j];
  float* o = acc + (long)d*HSZ + j*4;
  atomicAdd(o+0, alpha*hv.x);
  atomicAdd(o+1, alpha*hv.y);
  atomicAdd(o+2, alpha*hv.z);
  atomicAdd(o+3, alpha*hv.w);
}

__global__ void inter_bias_k(const float* __restrict__ acc2, const float* __restrict__ bias,
                             float* __restrict__ isec)
{
  int i = blockIdx.x*256 + threadIdx.x;   // exactly 64*128
  isec[i] = acc2[i] + bias[i & 127];
}

__global__ __launch_bounds__(256)
void fusion_k(const float* __restrict__ seq, const float* __restrict__ intra,
              const float* __restrict__ isec, const int* __restrict__ sid,
              const float* __restrict__ fw, const float* __restrict__ fb,
              float* __restrict__ out, int n)
{
  int i = blockIdx.x*4 + (threadIdx.x >> 6);
  int l = threadIdx.x & 63;
  if (i >= n) return;
  int sc = sid[i];
  long b = (long)i*HSZ;
  long sb = (long)sc*HSZ;
  float acc = fw[l]     * seq[b + l]      + fw[64 + l]  * seq[b + 64 + l]
            + fw[128+l] * intra[b + l]    + fw[192 + l] * intra[b + 64 + l]
            + fw[256+l] * isec[sb + l]    + fw[320 + l] * isec[sb + 64 + l];
  #pragma unroll
  for (int m = 1; m < 64; m <<= 1) acc += __shfl_xor(acc, m, 64);
  if (l == 0) out[i] = acc + fb[0];
}

extern "C" void kernel_launch(void* const* d_in, const int* in_sizes, int n_in,
                              void* d_out, int out_size, void* d_ws, size_t ws_size,
                              hipStream_t stream)
{
  const float* x    = (const float*)d_in[0];
  const int*   iei  = (const int*)d_in[1];    // [2, 640000]
  const int*   eei  = (const int*)d_in[2];    // [2, 4096]
  const int*   sid  = (const int*)d_in[3];
  const float* wih0 = (const float*)d_in[4];
  const float* whh0 = (const float*)d_in[5];
  const float* bih0 = (const float*)d_in[6];
  const float* bhh0 = (const float*)d_in[7];
  const float* wih1 = (const float*)d_in[8];
  const float* whh1 = (const float*)d_in[9];
  const float* bih1 = (const float*)d_in[10];
  const float* bhh1 = (const float*)d_in[11];
  const float* iW   = (const float*)d_in[12];
  const float* ias  = (const float*)d_in[13];
  const float* iad  = (const float*)d_in[14];
  const float* ib   = (const float*)d_in[15];
  const float* eW   = (const float*)d_in[16];
  const float* eas  = (const float*)d_in[17];
  const float* ead  = (const float*)d_in[18];
  const float* eb   = (const float*)d_in[19];
  const float* fW   = (const float*)d_in[20];
  const float* fb   = (const float*)d_in[21];

  float* ws = (float*)d_ws;
  long off = 0;
  float* seq    = ws + off; off += 2560000;
  float* hintra = ws + off; off += 2560000;
  float* intra  = ws + off; off += 2560000;
  float* es     = ws + off; off += 20000;
  float* ed     = ws + off; off += 20000;
  int*   cnt    = (int*)(ws + off); off += 20000;
  int*   rowptr = (int*)(ws + off); off += 20004;
  int*   cursor = (int*)(ws + off); off += 20000;
  int*   csrc   = (int*)(ws + off); off += 640000;
  int*   scnt    = (int*)(ws + off); off += 64;
  int*   srowptr = (int*)(ws + off); off += 68;
  int*   scursor = (int*)(ws + off); off += 64;
  int*   slist   = (int*)(ws + off); off += 20000;
  float* w0p = ws + off; off += 24576;   // 384 x 64 packed
  float* u0p = ws + off; off += 49152;   // 384 x 128
  float* w1p = ws + off; off += 49152;
  float* u1p = ws + off; off += 49152;
  float* spool  = ws + off; off += 8192;
  float* hinter = ws + off; off += 8192;
  float* acc2   = ws + off; off += 8192;
  float* es2    = ws + off; off += 64;
  float* ed2    = ws + off; off += 64;
  unsigned* mx2 = (unsigned*)(ws + off); off += 64;
  float* den2   = ws + off; off += 64;
  float* wbf2   = ws + off; off += 4160;
  float* isec   = ws + off; off += 8192;
  // total ~8.6M floats = ~34.5 MB

  // 0) pack GRU weights k-major (tiny)
  wpack_k<<<24, 256, 0, stream>>>(wih0, w0p, 16);
  wpack_k<<<48, 256, 0, stream>>>(whh0, u0p, 32);
  wpack_k<<<48, 256, 0, stream>>>(wih1, w1p, 32);
  wpack_k<<<48, 256, 0, stream>>>(whh1, u1p, 32);

  // 1) fused 2-layer GRU -> seq_emb  (one dispatch)
  gru_fused<<<500, 256, 0, stream>>>(x, w0p, u0p, bih0, bhh0,
                                     w1p, u1p, bih1, bhh1, seq);

  // 2) intra GAT: transform + CSR build + atomic-free gather
  gat_transform<<<313, 256, 0, stream>>>(seq, iW, ias, iad, hintra, es, ed, NCOMP);
  zero_i   <<<(NCOMP+255)/256, 256, 0, stream>>>(cnt, NCOMP);
  zero_i   <<<1, 256, 0, stream>>>(scnt, NSEC);
  csr_count<<<(EINTRA+255)/256, 256, 0, stream>>>(iei + EINTRA, cnt, EINTRA);
  csr_count<<<(NCOMP+255)/256, 256, 0, stream>>>(sid, scnt, NCOMP);
  csr_scan <<<1, 1024, 0, stream>>>(cnt, rowptr, cursor, NCOMP);
  csr_scan <<<1, 1024, 0, stream>>>(scnt, srowptr, scursor, NSEC);
  csr_fill <<<(EINTRA+255)/256, 256, 0, stream>>>(iei, iei + EINTRA, cursor, csrc, EINTRA);
  csr_fill <<<(NCOMP+255)/256, 256, 0, stream>>>(nullptr, sid, scursor, slist, NCOMP);
  gat_gather<<<NCOMP/4, 256, 0, stream>>>(rowptr, csrc, es, ed, hintra, ib, intra, NCOMP);

  // 3) per-sector max pool via sector row lists
  sector_pool<<<NSEC, 256, 0, stream>>>(intra, srowptr, slist, spool);

  // 4) inter GAT (tiny: 64 nodes, 4096 edges — atomic path)
  gat_init<<<32, 256, 0, stream>>>(mx2, den2, acc2, NSEC);
  gat_transform<<<1, 256, 0, stream>>>(spool, eW, eas, ead, hinter, es2, ed2, NSEC);
  {
    int tot = EINTER + NSEC;
    edge_max    <<<(tot+255)/256, 256, 0, stream>>>(eei, eei+EINTER, es2, ed2, mx2, EINTER, NSEC);
    edge_sum    <<<(tot+255)/256, 256, 0, stream>>>(eei, eei+EINTER, es2, ed2, mx2, den2, wbf2, EINTER, NSEC);
    edge_scatter<<<(tot*32)/256, 256, 0, stream>>>(eei, eei+EINTER, wbf2, den2, hinter, acc2, EINTER, NSEC);
  }
  inter_bias_k<<<32, 256, 0, stream>>>(acc2, eb, isec);

  // 5) fusion -> output [20000]
  fusion_k<<<NCOMP/4, 256, 0, stream>>>(seq, intra, isec, sid, fW, fb, (float*)d_out, NCOMP);
}